// Round 7
// baseline (269.416 us; speedup 1.0000x reference)
//
// R18 = R17 resubmitted verbatim (previous round failed in infra, not in the
// kernel: "MI355X container failed twice", no counters returned).
// R17: R15's 4-phase counted-vmcnt schedule + PHASE PINNING: sched_barrier(0)
// at every phase boundary and explicit "s_waitcnt lgkmcnt(0)" after each
// pre-MFMA s_barrier (guide rule #18 / HK technique #4). Raw s_barrier alone
// is not a compiler fence — R12-R16's phases were being re-flattened by the
// scheduler into 2-phase-equivalent order (m233 signature). Rest unchanged.
#include <hip/hip_runtime.h>

#define NQ 4096
#define NK 8192
#define DIM 1024

typedef __attribute__((ext_vector_type(8))) short short8;
typedef __attribute__((ext_vector_type(4))) float floatx4;
typedef unsigned int u32;
typedef __attribute__((address_space(3))) u32 lds_u32;
typedef __attribute__((address_space(1))) const u32 glb_u32;

__device__ __forceinline__ void gload_lds16(const void* g, void* l) {
    __builtin_amdgcn_global_load_lds((glb_u32*)g, (lds_u32*)l, 16, 0, 0);
}

__device__ __forceinline__ unsigned short f32_bf16(float f) {
    unsigned int u = __float_as_uint(f);
    u += 0x7fff + ((u >> 16) & 1);
    return (unsigned short)(u >> 16);
}

#define SBAR()  __builtin_amdgcn_sched_barrier(0)
#define LGK0()  asm volatile("s_waitcnt lgkmcnt(0)" ::: "memory")

// ---------------------------------------------------------------------------
// Q prep + optional zero(out) + zero(lsum)
// ---------------------------------------------------------------------------
__global__ void prep_q_zero(const float* __restrict__ Q,
                            unsigned short* __restrict__ Qb,
                            float* __restrict__ inv_qn,
                            float* __restrict__ lsum,
                            float* __restrict__ out_zero) {
    int wave = threadIdx.x >> 6;
    int lane = threadIdx.x & 63;
    int row  = blockIdx.x * 4 + wave;
    const float* r = Q + (size_t)row * DIM;
    float s = 0.f;
#pragma unroll
    for (int c = 0; c < 4; ++c) {
        float4 f = *(const float4*)(r + c * 256 + lane * 4);
        s += f.x * f.x + f.y * f.y + f.z * f.z + f.w * f.w;
        ushort4 b;
        b.x = f32_bf16(f.x); b.y = f32_bf16(f.y);
        b.z = f32_bf16(f.z); b.w = f32_bf16(f.w);
        *(ushort4*)(Qb + (size_t)row * DIM + c * 256 + lane * 4) = b;
    }
#pragma unroll
    for (int off = 32; off > 0; off >>= 1) s += __shfl_xor(s, off);
    if (lane == 0) inv_qn[row] = 1.0f / sqrtf(s);

    float4 z = make_float4(0.f, 0.f, 0.f, 0.f);
    if (out_zero) {
#pragma unroll
        for (int c = 0; c < 4; ++c)
            *(float4*)(out_zero + (size_t)blockIdx.x * 4096 + c * 1024 + threadIdx.x * 4) = z;
    }
    if (blockIdx.x < 4)
        *(float4*)(lsum + blockIdx.x * 1024 + threadIdx.x * 4) = z;
}

// ---------------------------------------------------------------------------
// K prep: bf16 convert + 1/norm
// ---------------------------------------------------------------------------
__global__ void prep_norm_cvt(const float* __restrict__ src,
                              unsigned short* __restrict__ dst,
                              float* __restrict__ inv_norm) {
    int wave = threadIdx.x >> 6;
    int lane = threadIdx.x & 63;
    int row  = blockIdx.x * 4 + wave;
    const float* r = src + (size_t)row * DIM;
    float s = 0.f;
#pragma unroll
    for (int c = 0; c < 4; ++c) {
        float4 f = *(const float4*)(r + c * 256 + lane * 4);
        s += f.x * f.x + f.y * f.y + f.z * f.z + f.w * f.w;
        ushort4 b;
        b.x = f32_bf16(f.x); b.y = f32_bf16(f.y);
        b.z = f32_bf16(f.z); b.w = f32_bf16(f.w);
        *(ushort4*)(dst + (size_t)row * DIM + c * 256 + lane * 4) = b;
    }
#pragma unroll
    for (int off = 32; off > 0; off >>= 1) s += __shfl_xor(s, off);
    if (lane == 0) inv_norm[row] = 1.0f / sqrtf(s);
}

// ---------------------------------------------------------------------------
// transpose + convert: Kt[d][kn] = bf16(K[kn][d])
// ---------------------------------------------------------------------------
__global__ void transpose_cvt(const float* __restrict__ K,
                              unsigned short* __restrict__ Kt) {
    __shared__ float t[64][65];
    int kn0 = blockIdx.x * 64, d0 = blockIdx.y * 64;
    int tid = threadIdx.x;
    int r  = tid >> 4;
    int c4 = (tid & 15) * 4;
#pragma unroll
    for (int s = 0; s < 4; ++s) {
        int kk = s * 16 + r;
        float4 f = *(const float4*)(K + (size_t)(kn0 + kk) * DIM + d0 + c4);
        t[kk][c4 + 0] = f.x; t[kk][c4 + 1] = f.y;
        t[kk][c4 + 2] = f.z; t[kk][c4 + 3] = f.w;
    }
    __syncthreads();
#pragma unroll
    for (int s = 0; s < 4; ++s) {
        int dd = s * 16 + r;
        ushort4 b;
        b.x = f32_bf16(t[c4 + 0][dd]);
        b.y = f32_bf16(t[c4 + 1][dd]);
        b.z = f32_bf16(t[c4 + 2][dd]);
        b.w = f32_bf16(t[c4 + 3][dd]);
        *(ushort4*)(Kt + (size_t)(d0 + dd) * NK + kn0 + c4) = b;
    }
}

// ---------------------------------------------------------------------------
// GEMM 1 (R17): 256x256, BK=64, 8 waves, 4 pinned phases per K-tile;
// counted vmcnt(4) once per tile. Phase = {ds_reads + stage | SBAR | barrier
// | lgkmcnt(0)+SBAR | setprio MFMA | SBAR | barrier}.
// ---------------------------------------------------------------------------
__global__ __launch_bounds__(512, 2) void score_gemm(
        const unsigned short* __restrict__ Qb,
        const unsigned short* __restrict__ Kb,
        const float* __restrict__ inv_qn,
        const float* __restrict__ inv_kn,
        unsigned short* __restrict__ P,
        float* __restrict__ lsum) {
    __shared__ __align__(16) unsigned short A_lds[2][2][256 * 32];
    __shared__ __align__(16) unsigned short B_lds[2][2][256 * 32];

    int bid = blockIdx.x;
    int swz = (bid & 7) * 64 + (bid >> 3);
    int q0  = (swz & 15) * 256;
    int n0  = (swz >> 4) * 256;

    int tid  = threadIdx.x;
    int wave = tid >> 6, lane = tid & 63;
    int wm = wave >> 2, wn = wave & 3;       // 2 x 4 wave grid
    int quad = lane >> 4, l16 = lane & 15;
    int rcol = (quad ^ ((l16 >> 1) & 3)) * 8;

    int schunk = ((tid & 3) ^ ((tid >> 3) & 3)) * 8;
    const unsigned short* gA = Qb + (size_t)(q0 + (tid >> 2)) * DIM + schunk;
    const unsigned short* gB = Kb + (size_t)(n0 + (tid >> 2)) * DIM + schunk;

#define STG_A(t1, pan)                                                \
    do {                                                              \
        const unsigned short* _g = gA + (t1) * 64 + (pan) * 32;       \
        unsigned short* _l = &A_lds[(t1) & 1][pan][wave * 512];       \
        gload_lds16(_g, _l);                                          \
        gload_lds16(_g + (size_t)128 * DIM, _l + 4096);               \
    } while (0)
#define STG_B(t1, pan)                                                \
    do {                                                              \
        const unsigned short* _g = gB + (t1) * 64 + (pan) * 32;       \
        unsigned short* _l = &B_lds[(t1) & 1][pan][wave * 512];       \
        gload_lds16(_g, _l);                                          \
        gload_lds16(_g + (size_t)128 * DIM, _l + 4096);               \
    } while (0)

    floatx4 acc[8][4];
#pragma unroll
    for (int i = 0; i < 8; ++i)
#pragma unroll
        for (int j = 0; j < 4; ++j) acc[i][j] = (floatx4)(0.0f);

    short8 a[4][2], bA[2][2], bB[2][2];

    const int NT = 16;
    STG_A(0, 0); STG_A(0, 1); STG_B(0, 0); STG_B(0, 1);
    STG_B(1, 0); STG_B(1, 1);
    asm volatile("s_waitcnt vmcnt(4)" ::: "memory");
    SBAR();
    __builtin_amdgcn_s_barrier();

#pragma unroll 2
    for (int t = 0; t < NT; ++t) {
        const unsigned short* A0 = &A_lds[t & 1][0][0];
        const unsigned short* A1 = &A_lds[t & 1][1][0];
        const unsigned short* B0 = &B_lds[t & 1][0][0];
        const unsigned short* B1 = &B_lds[t & 1][1][0];
        const int ar = (wm * 128 + l16) * 32 + rcol;
        const int br = (wn * 64 + l16) * 32 + rcol;

        // ---- phase 1: read a(mi0-3)+b(nj0-1); stage A-pan0(t+1) ----
#pragma unroll
        for (int mi = 0; mi < 4; ++mi) {
            a[mi][0] = *(const short8*)&A0[ar + mi * 512];
            a[mi][1] = *(const short8*)&A1[ar + mi * 512];
        }
#pragma unroll
        for (int nj = 0; nj < 2; ++nj) {
            bA[nj][0] = *(const short8*)&B0[br + nj * 512];
            bA[nj][1] = *(const short8*)&B1[br + nj * 512];
        }
        if (t + 1 < NT) STG_A(t + 1, 0);
        SBAR();
        __builtin_amdgcn_s_barrier();
        LGK0(); SBAR();
        __builtin_amdgcn_s_setprio(1);
#pragma unroll
        for (int mi = 0; mi < 4; ++mi)
#pragma unroll
            for (int nj = 0; nj < 2; ++nj) {
                acc[mi][nj] = __builtin_amdgcn_mfma_f32_16x16x32_bf16(bA[nj][0], a[mi][0], acc[mi][nj], 0, 0, 0);
                acc[mi][nj] = __builtin_amdgcn_mfma_f32_16x16x32_bf16(bA[nj][1], a[mi][1], acc[mi][nj], 0, 0, 0);
            }
        __builtin_amdgcn_s_setprio(0);
        SBAR();
        __builtin_amdgcn_s_barrier();

        // ---- phase 2: read b(nj2-3); stage A-pan1(t+1) ----
#pragma unroll
        for (int nj = 0; nj < 2; ++nj) {
            bB[nj][0] = *(const short8*)&B0[br + 1024 + nj * 512];
            bB[nj][1] = *(const short8*)&B1[br + 1024 + nj * 512];
        }
        if (t + 1 < NT) STG_A(t + 1, 1);
        SBAR();
        __builtin_amdgcn_s_barrier();
        LGK0(); SBAR();
        __builtin_amdgcn_s_setprio(1);
#pragma unroll
        for (int mi = 0; mi < 4; ++mi)
#pragma unroll
            for (int nj = 0; nj < 2; ++nj) {
                acc[mi][2 + nj] = __builtin_amdgcn_mfma_f32_16x16x32_bf16(bB[nj][0], a[mi][0], acc[mi][2 + nj], 0, 0, 0);
                acc[mi][2 + nj] = __builtin_amdgcn_mfma_f32_16x16x32_bf16(bB[nj][1], a[mi][1], acc[mi][2 + nj], 0, 0, 0);
            }
        __builtin_amdgcn_s_setprio(0);
        SBAR();
        __builtin_amdgcn_s_barrier();

        // ---- phase 3: read a(mi4-7); stage B-pan0(t+2) ----
#pragma unroll
        for (int mi = 0; mi < 4; ++mi) {
            a[mi][0] = *(const short8*)&A0[ar + 2048 + mi * 512];
            a[mi][1] = *(const short8*)&A1[ar + 2048 + mi * 512];
        }
        if (t + 2 < NT) STG_B(t + 2, 0);
        SBAR();
        __builtin_amdgcn_s_barrier();
        LGK0(); SBAR();
        __builtin_amdgcn_s_setprio(1);
#pragma unroll
        for (int mi = 0; mi < 4; ++mi)
#pragma unroll
            for (int nj = 0; nj < 2; ++nj) {
                acc[4 + mi][2 + nj] = __builtin_amdgcn_mfma_f32_16x16x32_bf16(bB[nj][0], a[mi][0], acc[4 + mi][2 + nj], 0, 0, 0);
                acc[4 + mi][2 + nj] = __builtin_amdgcn_mfma_f32_16x16x32_bf16(bB[nj][1], a[mi][1], acc[4 + mi][2 + nj], 0, 0, 0);
            }
        __builtin_amdgcn_s_setprio(0);
        SBAR();
        __builtin_amdgcn_s_barrier();

        // ---- phase 4: pure MFMA; stage B-pan1(t+2); counted wait ----
        if (t + 2 < NT) STG_B(t + 2, 1);
        SBAR();
        __builtin_amdgcn_s_barrier();
        SBAR();
        __builtin_amdgcn_s_setprio(1);
#pragma unroll
        for (int mi = 0; mi < 4; ++mi)
#pragma unroll
            for (int nj = 0; nj < 2; ++nj) {
                acc[4 + mi][nj] = __builtin_amdgcn_mfma_f32_16x16x32_bf16(bA[nj][0], a[mi][0], acc[4 + mi][nj], 0, 0, 0);
                acc[4 + mi][nj] = __builtin_amdgcn_mfma_f32_16x16x32_bf16(bA[nj][1], a[mi][1], acc[4 + mi][nj], 0, 0, 0);
            }
        __builtin_amdgcn_s_setprio(0);
        SBAR();
        if (t + 2 < NT) {
            asm volatile("s_waitcnt vmcnt(4)" ::: "memory");
        } else if (t + 1 < NT) {
            asm volatile("s_waitcnt vmcnt(0)" ::: "memory");
        }
        __builtin_amdgcn_s_barrier();
    }
#undef STG_A
#undef STG_B

    // epilogue: exp(score * iqn * ikn), bf16 P store, lsum atomics
#pragma unroll
    for (int i = 0; i < 8; ++i) {
        int qrow = q0 + wm * 128 + i * 16 + l16;
        float iqn = inv_qn[qrow];
        float rs = 0.f;
#pragma unroll
        for (int j = 0; j < 4; ++j) {
            int ncol = n0 + wn * 64 + j * 16 + quad * 4;
            float4 ik = *(const float4*)&inv_kn[ncol];
            float p0 = __expf(acc[i][j][0] * iqn * ik.x);
            float p1 = __expf(acc[i][j][1] * iqn * ik.y);
            float p2 = __expf(acc[i][j][2] * iqn * ik.z);
            float p3 = __expf(acc[i][j][3] * iqn * ik.w);
            ushort4 pb;
            pb.x = f32_bf16(p0); pb.y = f32_bf16(p1);
            pb.z = f32_bf16(p2); pb.w = f32_bf16(p3);
            *(ushort4*)&P[(size_t)qrow * NK + ncol] = pb;
            rs += p0 + p1 + p2 + p3;
        }
        rs += __shfl_xor(rs, 16);
        rs += __shfl_xor(rs, 32);
        if (quad == 0) atomicAdd(&lsum[qrow], rs);
    }
}

// ---------------------------------------------------------------------------
// GEMM 2 tier-1 (R17): same pinned 4-phase schedule, split-K z=4 (grid 256),
// OPERAND-SWAPPED, float4 partial stores into part[z][q][d].
// ---------------------------------------------------------------------------
__global__ __launch_bounds__(512, 2) void ctx_gemm_st(
        const unsigned short* __restrict__ P,
        const unsigned short* __restrict__ Kt,
        float* __restrict__ part) {
    __shared__ __align__(16) unsigned short A_lds[2][2][256 * 32];
    __shared__ __align__(16) unsigned short B_lds[2][2][256 * 32];

    int bid = blockIdx.x;
    int swz = (bid & 7) * 32 + (bid >> 3);
    int z  = swz >> 6;
    int y  = (swz >> 2) & 15;
    int x  = swz & 3;
    int q0 = y * 256;
    int d0 = x * 256;
    int kbase = z * (NK / 4);

    int tid  = threadIdx.x;
    int wave = tid >> 6, lane = tid & 63;
    int wm = wave >> 2, wn = wave & 3;
    int quad = lane >> 4, l16 = lane & 15;
    int rcol = (quad ^ ((l16 >> 1) & 3)) * 8;

    int schunk = ((tid & 3) ^ ((tid >> 3) & 3)) * 8;
    const unsigned short* gA = P  + (size_t)(q0 + (tid >> 2)) * NK + kbase + schunk;
    const unsigned short* gB = Kt + (size_t)(d0 + (tid >> 2)) * NK + kbase + schunk;

#define STG_A(t1, pan)                                                \
    do {                                                              \
        const unsigned short* _g = gA + (t1) * 64 + (pan) * 32;       \
        unsigned short* _l = &A_lds[(t1) & 1][pan][wave * 512];       \
        gload_lds16(_g, _l);                                          \
        gload_lds16(_g + (size_t)128 * NK, _l + 4096);                \
    } while (0)
#define STG_B(t1, pan)                                                \
    do {                                                              \
        const unsigned short* _g = gB + (t1) * 64 + (pan) * 32;       \
        unsigned short* _l = &B_lds[(t1) & 1][pan][wave * 512];       \
        gload_lds16(_g, _l);                                          \
        gload_lds16(_g + (size_t)128 * NK, _l + 4096);                \
    } while (0)

    floatx4 acc[8][4];
#pragma unroll
    for (int i = 0; i < 8; ++i)
#pragma unroll
        for (int j = 0; j < 4; ++j) acc[i][j] = (floatx4)(0.0f);

    short8 a[4][2], bA[2][2], bB[2][2];

    const int NT = (NK / 4) / 64;   // 32
    STG_A(0, 0); STG_A(0, 1); STG_B(0, 0); STG_B(0, 1);
    STG_B(1, 0); STG_B(1, 1);
    asm volatile("s_waitcnt vmcnt(4)" ::: "memory");
    SBAR();
    __builtin_amdgcn_s_barrier();

#pragma unroll 2
    for (int t = 0; t < NT; ++t) {
        const unsigned short* A0 = &A_lds[t & 1][0][0];
        const unsigned short* A1 = &A_lds[t & 1][1][0];
        const unsigned short* B0 = &B_lds[t & 1][0][0];
        const unsigned short* B1 = &B_lds[t & 1][1][0];
        const int ar = (wm * 128 + l16) * 32 + rcol;
        const int br = (wn * 64 + l16) * 32 + rcol;

        // ---- phase 1 ----
#pragma unroll
        for (int mi = 0; mi < 4; ++mi) {
            a[mi][0] = *(const short8*)&A0[ar + mi * 512];
            a[mi][1] = *(const short8*)&A1[ar + mi * 512];
        }
#pragma unroll
        for (int nj = 0; nj < 2; ++nj) {
            bA[nj][0] = *(const short8*)&B0[br + nj * 512];
            bA[nj][1] = *(const short8*)&B1[br + nj * 512];
        }
        if (t + 1 < NT) STG_A(t + 1, 0);
        SBAR();
        __builtin_amdgcn_s_barrier();
        LGK0(); SBAR();
        __builtin_amdgcn_s_setprio(1);
#pragma unroll
        for (int mi = 0; mi < 4; ++mi)
#pragma unroll
            for (int nj = 0; nj < 2; ++nj) {
                acc[mi][nj] = __builtin_amdgcn_mfma_f32_16x16x32_bf16(bA[nj][0], a[mi][0], acc[mi][nj], 0, 0, 0);
                acc[mi][nj] = __builtin_amdgcn_mfma_f32_16x16x32_bf16(bA[nj][1], a[mi][1], acc[mi][nj], 0, 0, 0);
            }
        __builtin_amdgcn_s_setprio(0);
        SBAR();
        __builtin_amdgcn_s_barrier();

        // ---- phase 2 ----
#pragma unroll
        for (int nj = 0; nj < 2; ++nj) {
            bB[nj][0] = *(const short8*)&B0[br + 1024 + nj * 512];
            bB[nj][1] = *(const short8*)&B1[br + 1024 + nj * 512];
        }
        if (t + 1 < NT) STG_A(t + 1, 1);
        SBAR();
        __builtin_amdgcn_s_barrier();
        LGK0(); SBAR();
        __builtin_amdgcn_s_setprio(1);
#pragma unroll
        for (int mi = 0; mi < 4; ++mi)
#pragma unroll
            for (int nj = 0; nj < 2; ++nj) {
                acc[mi][2 + nj] = __builtin_amdgcn_mfma_f32_16x16x32_bf16(bB[nj][0], a[mi][0], acc[mi][2 + nj], 0, 0, 0);
                acc[mi][2 + nj] = __builtin_amdgcn_mfma_f32_16x16x32_bf16(bB[nj][1], a[mi][1], acc[mi][2 + nj], 0, 0, 0);
            }
        __builtin_amdgcn_s_setprio(0);
        SBAR();
        __builtin_amdgcn_s_barrier();

        // ---- phase 3 ----
#pragma unroll
        for (int mi = 0; mi < 4; ++mi) {
            a[mi][0] = *(const short8*)&A0[ar + 2048 + mi * 512];
            a[mi][1] = *(const short8*)&A1[ar + 2048 + mi * 512];
        }
        if (t + 2 < NT) STG_B(t + 2, 0);
        SBAR();
        __builtin_amdgcn_s_barrier();
        LGK0(); SBAR();
        __builtin_amdgcn_s_setprio(1);
#pragma unroll
        for (int mi = 0; mi < 4; ++mi)
#pragma unroll
            for (int nj = 0; nj < 2; ++nj) {
                acc[4 + mi][2 + nj] = __builtin_amdgcn_mfma_f32_16x16x32_bf16(bB[nj][0], a[mi][0], acc[4 + mi][2 + nj], 0, 0, 0);
                acc[4 + mi][2 + nj] = __builtin_amdgcn_mfma_f32_16x16x32_bf16(bB[nj][1], a[mi][1], acc[4 + mi][2 + nj], 0, 0, 0);
            }
        __builtin_amdgcn_s_setprio(0);
        SBAR();
        __builtin_amdgcn_s_barrier();

        // ---- phase 4 ----
        if (t + 2 < NT) STG_B(t + 2, 1);
        SBAR();
        __builtin_amdgcn_s_barrier();
        SBAR();
        __builtin_amdgcn_s_setprio(1);
#pragma unroll
        for (int mi = 0; mi < 4; ++mi)
#pragma unroll
            for (int nj = 0; nj < 2; ++nj) {
                acc[4 + mi][nj] = __builtin_amdgcn_mfma_f32_16x16x32_bf16(bA[nj][0], a[mi][0], acc[4 + mi][nj], 0, 0, 0);
                acc[4 + mi][nj] = __builtin_amdgcn_mfma_f32_16x16x32_bf16(bA[nj][1], a[mi][1], acc[4 + mi][nj], 0, 0, 0);
            }
        __builtin_amdgcn_s_setprio(0);
        SBAR();
        if (t + 2 < NT) {
            asm volatile("s_waitcnt vmcnt(4)" ::: "memory");
        } else if (t + 1 < NT) {
            asm volatile("s_waitcnt vmcnt(0)" ::: "memory");
        }
        __builtin_amdgcn_s_barrier();
    }
#undef STG_A
#undef STG_B

    float* pslice = part + (size_t)z * NQ * DIM;
#pragma unroll
    for (int i = 0; i < 8; ++i) {
        int qrow = q0 + wm * 128 + i * 16 + l16;
#pragma unroll
        for (int j = 0; j < 4; ++j) {
            int dcol = d0 + wn * 64 + j * 16 + quad * 4;
            float4 v;
            v.x = acc[i][j][0]; v.y = acc[i][j][1];
            v.z = acc[i][j][2]; v.w = acc[i][j][3];
            *(float4*)&pslice[(size_t)qrow * DIM + dcol] = v;
        }
    }
}

// ---------------------------------------------------------------------------
// reduce: out[q][d] = (sum_z part[z][q][d]) / lsum[q]
// ---------------------------------------------------------------------------
__global__ void reduce_out(const float* __restrict__ part,
                           const float* __restrict__ lsum,
                           float* __restrict__ out) {
    size_t idx = ((size_t)blockIdx.x * 256 + threadIdx.x) * 4;
    int q = (int)(idx >> 10);
    float inv = 1.0f / lsum[q];
    const size_t S = (size_t)NQ * DIM;
    float4 s0 = *(const float4*)(part + idx);
    float4 s1 = *(const float4*)(part + S + idx);
    float4 s2 = *(const float4*)(part + 2 * S + idx);
    float4 s3 = *(const float4*)(part + 3 * S + idx);
    float4 o;
    o.x = (s0.x + s1.x + s2.x + s3.x) * inv;
    o.y = (s0.y + s1.y + s2.y + s3.y) * inv;
    o.z = (s0.z + s1.z + s2.z + s3.z) * inv;
    o.w = (s0.w + s1.w + s2.w + s3.w) * inv;
    *(float4*)(out + idx) = o;
}

// ---------------------------------------------------------------------------
// GEMM 2 tier-2 (exact R10): atomics into pre-zeroed out.
// ---------------------------------------------------------------------------
__global__ void ctx_gemm(const unsigned short* __restrict__ P,
                         const unsigned short* __restrict__ Kt,
                         const float* __restrict__ lsum,
                         float* __restrict__ out) {
    __shared__ __align__(16) unsigned short As[128 * 32];
    __shared__ __align__(16) unsigned short Bs[128 * 32];
    int id = blockIdx.x;
    int r8 = id & 7;
    int t  = id >> 3;
    int x  = t & 7;
    int g  = ((t >> 3) << 3) | r8;
    int y  = g & 31;
    int z  = g >> 5;
    int q0 = y * 128;
    int d0 = x * 128;
    int kbase = z * (NK / 4);

    int tid = threadIdx.x;
    int wave = tid >> 6, lane = tid & 63;
    int wm = wave >> 1, wn = wave & 1;
    int quad = lane >> 4, l16 = lane & 15;

    int srow   = wave * 32 + (lane >> 2);
    int schunk = (((lane & 3) ^ ((lane >> 3) & 3))) * 8;
    const unsigned short* gA0 = P + (size_t)(q0 + srow) * NK + kbase + schunk;
    const unsigned short* gA1 = gA0 + (size_t)16 * NK;
    const unsigned short* gB0 = Kt + (size_t)(d0 + srow) * NK + kbase + schunk;
    const unsigned short* gB1 = gB0 + (size_t)16 * NK;
    unsigned short* lA0 = As + wave * 32 * 32;
    unsigned short* lA1 = lA0 + 16 * 32;
    unsigned short* lB0 = Bs + wave * 32 * 32;
    unsigned short* lB1 = lB0 + 16 * 32;

    int rcol = (quad ^ ((l16 >> 1) & 3)) * 8;

    floatx4 acc[4][4];
#pragma unroll
    for (int i = 0; i < 4; ++i)
#pragma unroll
        for (int j = 0; j < 4; ++j) acc[i][j] = (floatx4)(0.0f);

    for (int kb = 0; kb < (NK / 4) / 32; ++kb) {
        int k0 = kb * 32;
        __syncthreads();
        gload_lds16(gA0 + k0, lA0);
        gload_lds16(gA1 + k0, lA1);
        gload_lds16(gB0 + k0, lB0);
        gload_lds16(gB1 + k0, lB1);
        __syncthreads();
        short8 a[4], b[4];
#pragma unroll
        for (int i = 0; i < 4; ++i)
            a[i] = *(const short8*)&As[(wm * 64 + i * 16 + l16) * 32 + rcol];
#pragma unroll
        for (int j = 0; j < 4; ++j)
            b[j] = *(const short8*)&Bs[(wn * 64 + j * 16 + l16) * 32 + rcol];
#pragma unroll
        for (int i = 0; i < 4; ++i)
#pragma unroll
            for (int j = 0; j < 4; ++j)
                acc[i][j] = __builtin_amdgcn_mfma_f32_16x16x32_bf16(a[i], b[j], acc[i][j], 0, 0, 0);
    }

#pragma unroll
    for (int i = 0; i < 4; ++i) {
        float invl[4];
#pragma unroll
        for (int r = 0; r < 4; ++r)
            invl[r] = 1.0f / lsum[q0 + wm * 64 + i * 16 + quad * 4 + r];
#pragma unroll
        for (int j = 0; j < 4; ++j) {
#pragma unroll
            for (int r = 0; r < 4; ++r) {
                int qrow = q0 + wm * 64 + i * 16 + quad * 4 + r;
                int dcol = d0 + wn * 64 + j * 16 + l16;
                atomicAdd(&out[(size_t)qrow * DIM + dcol], acc[i][j][r] * invl[r]);
            }
        }
    }
}

// ---------------------------------------------------------------------------
// Path D fallback (ws too small) — correct but slow.
// ---------------------------------------------------------------------------
__global__ void fused_fallback(const float* __restrict__ Q,
                               const float* __restrict__ K,
                               float* __restrict__ out) {
    int wave = threadIdx.x >> 6, lane = threadIdx.x & 63;
    int q0 = blockIdx.x * 16 + wave * 4;
    float qv[4][16], acc[4][16], iqn[4], ls[4];
#pragma unroll
    for (int r = 0; r < 4; ++r) {
        float s = 0.f;
#pragma unroll
        for (int c = 0; c < 4; ++c) {
            float4 f = *(const float4*)(Q + (size_t)(q0 + r) * DIM + c * 256 + lane * 4);
            qv[r][c * 4 + 0] = f.x; qv[r][c * 4 + 1] = f.y;
            qv[r][c * 4 + 2] = f.z; qv[r][c * 4 + 3] = f.w;
            s += f.x * f.x + f.y * f.y + f.z * f.z + f.w * f.w;
        }
#pragma unroll
        for (int off = 32; off > 0; off >>= 1) s += __shfl_xor(s, off);
        iqn[r] = 1.0f / sqrtf(s);
        ls[r] = 0.f;
#pragma unroll
        for (int t = 0; t < 16; ++t) acc[r][t] = 0.f;
    }
    for (int k = 0; k < NK; ++k) {
        const float* kr = K + (size_t)k * DIM;
        float kv[16], ss = 0.f;
#pragma unroll
        for (int c = 0; c < 4; ++c) {
            float4 f = *(const float4*)(kr + c * 256 + lane * 4);
            kv[c * 4 + 0] = f.x; kv[c * 4 + 1] = f.y;
            kv[c * 4 + 2] = f.z; kv[c * 4 + 3] = f.w;
            ss += f.x * f.x + f.y * f.y + f.z * f.z + f.w * f.w;
        }
        float d0 = 0.f, d1 = 0.f, d2 = 0.f, d3 = 0.f;
#pragma unroll
        for (int t = 0; t < 16; ++t) {
            d0 += qv[0][t] * kv[t]; d1 += qv[1][t] * kv[t];
            d2 += qv[2][t] * kv[t]; d3 += qv[3][t] * kv[t];
        }
#pragma unroll
        for (int off = 32; off > 0; off >>= 1) {
            ss += __shfl_xor(ss, off);
            d0 += __shfl_xor(d0, off); d1 += __shfl_xor(d1, off);
            d2 += __shfl_xor(d2, off); d3 += __shfl_xor(d3, off);
        }
        float ikn = 1.0f / sqrtf(ss);
        float p0 = __expf(d0 * iqn[0] * ikn), p1 = __expf(d1 * iqn[1] * ikn);
        float p2 = __expf(d2 * iqn[2] * ikn), p3 = __expf(d3 * iqn[3] * ikn);
        ls[0] += p0; ls[1] += p1; ls[2] += p2; ls[3] += p3;
#pragma unroll
        for (int t = 0; t < 16; ++t) {
            acc[0][t] += p0 * kv[t]; acc[1][t] += p1 * kv[t];
            acc[2][t] += p2 * kv[t]; acc[3][t] += p3 * kv[t];
        }
    }
#pragma unroll
    for (int r = 0; r < 4; ++r) {
        float inv = 1.0f / ls[r];
#pragma unroll
        for (int c = 0; c < 4; ++c) {
            float4 o;
            o.x = acc[r][c * 4 + 0] * inv; o.y = acc[r][c * 4 + 1] * inv;
            o.z = acc[r][c * 4 + 2] * inv; o.w = acc[r][c * 4 + 3] * inv;
            *(float4*)(out + (size_t)(q0 + r) * DIM + c * 256 + lane * 4) = o;
        }
    }
}

// ---------------------------------------------------------------------------
// launch — tiers:
//  T1 (ws>=152M+64K): Kt[0,16M) overlap Qb/Kb, P[24,88M), part[88,152M),
//                     scalars @152M; ctx_gemm_st + reduce_out.
//  T2 (ws>=88M+64K):  exact R10 (atomics).
//  else: fallback.
// ---------------------------------------------------------------------------
extern "C" void kernel_launch(void* const* d_in, const int* in_sizes, int n_in,
                              void* d_out, int out_size, void* d_ws, size_t ws_size,
                              hipStream_t stream) {
    const float* Q = (const float*)d_in[0];
    const float* K = (const float*)d_in[1];
    float* out = (float*)d_out;
    char* ws = (char*)d_ws;

    const size_t REQ_T1 = ((size_t)152u << 20) + 65536;
    const size_t REQ_T2 = ((size_t)88u << 20) + 65536;

    if (ws_size >= REQ_T1) {
        unsigned short* Kt = (unsigned short*)(ws);
        unsigned short* Qb = (unsigned short*)(ws);
        unsigned short* Kb = (unsigned short*)(ws + (size_t)(8u << 20));
        unsigned short* P  = (unsigned short*)(ws + (size_t)(24u << 20));
        float* part   = (float*)(ws + (size_t)(88u << 20));
        float* inv_qn = (float*)(ws + (size_t)(152u << 20));
        float* inv_kn = (float*)(ws + (size_t)(152u << 20) + 16384);
        float* lsum   = (float*)(ws + (size_t)(152u << 20) + 49152);

        prep_q_zero<<<NQ / 4, 256, 0, stream>>>(Q, Qb, inv_qn, lsum, nullptr);
        prep_norm_cvt<<<NK / 4, 256, 0, stream>>>(K, Kb, inv_kn);
        score_gemm<<<512, 512, 0, stream>>>(Qb, Kb, inv_qn, inv_kn, P, lsum);
        transpose_cvt<<<dim3(NK / 64, DIM / 64), 256, 0, stream>>>(K, Kt);
        ctx_gemm_st<<<256, 512, 0, stream>>>(P, Kt, part);
        reduce_out<<<NQ * DIM / 1024, 256, 0, stream>>>(part, lsum, out);
    } else if (ws_size >= REQ_T2) {
        unsigned short* Kt = (unsigned short*)(ws);
        unsigned short* Qb = (unsigned short*)(ws);
        unsigned short* Kb = (unsigned short*)(ws + (size_t)(8u << 20));
        unsigned short* P  = (unsigned short*)(ws + (size_t)(24u << 20));
        float* inv_qn = (float*)(ws + (size_t)(88u << 20));
        float* inv_kn = (float*)(ws + (size_t)(88u << 20) + 16384);
        float* lsum   = (float*)(ws + (size_t)(88u << 20) + 49152);

        prep_q_zero<<<NQ / 4, 256, 0, stream>>>(Q, Qb, inv_qn, lsum, out);
        prep_norm_cvt<<<NK / 4, 256, 0, stream>>>(K, Kb, inv_kn);
        score_gemm<<<512, 512, 0, stream>>>(Qb, Kb, inv_qn, inv_kn, P, lsum);
        transpose_cvt<<<dim3(NK / 64, DIM / 64), 256, 0, stream>>>(K, Kt);
        ctx_gemm<<<1024, 256, 0, stream>>>(P, Kt, lsum, out);
    } else {
        fused_fallback<<<NQ / 16, 256, 0, stream>>>(Q, K, out);
    }
}

// Round 8
// 249.116 us; speedup vs baseline: 1.0815x; 1.0815x over previous
//
// R19: bank the proven GEMMs (score=R12, ctx=R13, both ~760 TF plateau after
// 5 schedule nulls) and cut pipeline overhead: (1) part stored as bf16
// (-64 MB HBM), (2) transpose reads Kb bf16 not K f32 (-17 MB), Kt moved to
// 120M to un-alias Kb, (3) preps merged into one prep_all launch.
// T2/fallback tiers unchanged.
#include <hip/hip_runtime.h>

#define NQ 4096
#define NK 8192
#define DIM 1024

typedef __attribute__((ext_vector_type(8))) short short8;
typedef __attribute__((ext_vector_type(4))) float floatx4;
typedef unsigned int u32;
typedef __attribute__((address_space(3))) u32 lds_u32;
typedef __attribute__((address_space(1))) const u32 glb_u32;

__device__ __forceinline__ void gload_lds16(const void* g, void* l) {
    __builtin_amdgcn_global_load_lds((glb_u32*)g, (lds_u32*)l, 16, 0, 0);
}

__device__ __forceinline__ unsigned short f32_bf16(float f) {
    unsigned int u = __float_as_uint(f);
    u += 0x7fff + ((u >> 16) & 1);
    return (unsigned short)(u >> 16);
}

__device__ __forceinline__ float bf16_f32(unsigned short u) {
    return __uint_as_float((u32)u << 16);
}

// ---------------------------------------------------------------------------
// prep_all: blocks [0,NQ/4) process Q rows (+ optional zero(out) + zero lsum),
// blocks [NQ/4, NQ/4+NK/4) process K rows. bf16 convert + 1/norm.
// ---------------------------------------------------------------------------
__global__ void prep_all(const float* __restrict__ Q,
                         const float* __restrict__ K,
                         unsigned short* __restrict__ Qb,
                         unsigned short* __restrict__ Kb,
                         float* __restrict__ inv_qn,
                         float* __restrict__ inv_kn,
                         float* __restrict__ lsum,
                         float* __restrict__ out_zero) {
    int wave = threadIdx.x >> 6;
    int lane = threadIdx.x & 63;
    int bid  = blockIdx.x;
    const float* src;
    unsigned short* dst;
    float* invp;
    int row;
    if (bid < NQ / 4) {
        row = bid * 4 + wave; src = Q; dst = Qb; invp = inv_qn;
    } else {
        row = (bid - NQ / 4) * 4 + wave; src = K; dst = Kb; invp = inv_kn;
    }
    const float* r = src + (size_t)row * DIM;
    float s = 0.f;
#pragma unroll
    for (int c = 0; c < 4; ++c) {
        float4 f = *(const float4*)(r + c * 256 + lane * 4);
        s += f.x * f.x + f.y * f.y + f.z * f.z + f.w * f.w;
        ushort4 b;
        b.x = f32_bf16(f.x); b.y = f32_bf16(f.y);
        b.z = f32_bf16(f.z); b.w = f32_bf16(f.w);
        *(ushort4*)(dst + (size_t)row * DIM + c * 256 + lane * 4) = b;
    }
#pragma unroll
    for (int off = 32; off > 0; off >>= 1) s += __shfl_xor(s, off);
    if (lane == 0) invp[row] = 1.0f / sqrtf(s);

    if (bid < NQ / 4) {
        float4 z = make_float4(0.f, 0.f, 0.f, 0.f);
        if (out_zero) {
#pragma unroll
            for (int c = 0; c < 4; ++c)
                *(float4*)(out_zero + (size_t)bid * 4096 + c * 1024 + threadIdx.x * 4) = z;
        }
        if (bid < 4)
            *(float4*)(lsum + bid * 1024 + threadIdx.x * 4) = z;
    }
}

// ---------------------------------------------------------------------------
// transpose (bf16 -> bf16): Kt[d][kn] = Kb[kn][d]   (T1 path)
// ---------------------------------------------------------------------------
__global__ void transpose_bf16(const unsigned short* __restrict__ Kb,
                               unsigned short* __restrict__ Kt) {
    __shared__ unsigned short t[64][66];
    int kn0 = blockIdx.x * 64, d0 = blockIdx.y * 64;
    int tid = threadIdx.x;
    int r  = tid >> 4;
    int c4 = (tid & 15) * 4;
#pragma unroll
    for (int s = 0; s < 4; ++s) {
        int kk = s * 16 + r;
        ushort4 v = *(const ushort4*)(Kb + (size_t)(kn0 + kk) * DIM + d0 + c4);
        t[kk][c4 + 0] = v.x; t[kk][c4 + 1] = v.y;
        t[kk][c4 + 2] = v.z; t[kk][c4 + 3] = v.w;
    }
    __syncthreads();
#pragma unroll
    for (int s = 0; s < 4; ++s) {
        int dd = s * 16 + r;
        ushort4 b;
        b.x = t[c4 + 0][dd]; b.y = t[c4 + 1][dd];
        b.z = t[c4 + 2][dd]; b.w = t[c4 + 3][dd];
        *(ushort4*)(Kt + (size_t)(d0 + dd) * NK + kn0 + c4) = b;
    }
}

// ---------------------------------------------------------------------------
// transpose + convert (f32 -> bf16): Kt[d][kn] = bf16(K[kn][d])  (T2 legacy)
// ---------------------------------------------------------------------------
__global__ void transpose_cvt(const float* __restrict__ K,
                              unsigned short* __restrict__ Kt) {
    __shared__ float t[64][65];
    int kn0 = blockIdx.x * 64, d0 = blockIdx.y * 64;
    int tid = threadIdx.x;
    int r  = tid >> 4;
    int c4 = (tid & 15) * 4;
#pragma unroll
    for (int s = 0; s < 4; ++s) {
        int kk = s * 16 + r;
        float4 f = *(const float4*)(K + (size_t)(kn0 + kk) * DIM + d0 + c4);
        t[kk][c4 + 0] = f.x; t[kk][c4 + 1] = f.y;
        t[kk][c4 + 2] = f.z; t[kk][c4 + 3] = f.w;
    }
    __syncthreads();
#pragma unroll
    for (int s = 0; s < 4; ++s) {
        int dd = s * 16 + r;
        ushort4 b;
        b.x = f32_bf16(t[c4 + 0][dd]);
        b.y = f32_bf16(t[c4 + 1][dd]);
        b.z = f32_bf16(t[c4 + 2][dd]);
        b.w = f32_bf16(t[c4 + 3][dd]);
        *(ushort4*)(Kt + (size_t)(d0 + dd) * NK + kn0 + c4) = b;
    }
}

// ---------------------------------------------------------------------------
// GEMM 1 (R12, proven 90 µs): 256x256 tile, BK=64, 8 waves, 4 phases/K-tile,
// raw s_barrier + vmcnt(0) drain once per tile, setprio, XOR swizzle,
// chunked XCD swizzle. Epilogue: exp + bf16 P store + lsum atomics.
// ---------------------------------------------------------------------------
__global__ __launch_bounds__(512, 2) void score_gemm(
        const unsigned short* __restrict__ Qb,
        const unsigned short* __restrict__ Kb,
        const float* __restrict__ inv_qn,
        const float* __restrict__ inv_kn,
        unsigned short* __restrict__ P,
        float* __restrict__ lsum) {
    __shared__ __align__(16) unsigned short A_lds[2][2][256 * 32];
    __shared__ __align__(16) unsigned short B_lds[2][2][256 * 32];

    int bid = blockIdx.x;
    int swz = (bid & 7) * 64 + (bid >> 3);
    int q0  = (swz & 15) * 256;
    int n0  = (swz >> 4) * 256;

    int tid  = threadIdx.x;
    int wave = tid >> 6, lane = tid & 63;
    int wm = wave >> 2, wn = wave & 3;       // 2 x 4 wave grid
    int quad = lane >> 4, l16 = lane & 15;
    int rcol = (quad ^ ((l16 >> 1) & 3)) * 8;

    int schunk = ((tid & 3) ^ ((tid >> 3) & 3)) * 8;
    const unsigned short* gA = Qb + (size_t)(q0 + (tid >> 2)) * DIM + schunk;
    const unsigned short* gB = Kb + (size_t)(n0 + (tid >> 2)) * DIM + schunk;

#define STG_A(t1, pan)                                                \
    do {                                                              \
        const unsigned short* _g = gA + (t1) * 64 + (pan) * 32;       \
        unsigned short* _l = &A_lds[(t1) & 1][pan][wave * 512];       \
        gload_lds16(_g, _l);                                          \
        gload_lds16(_g + (size_t)128 * DIM, _l + 4096);               \
    } while (0)
#define STG_B(t1, pan)                                                \
    do {                                                              \
        const unsigned short* _g = gB + (t1) * 64 + (pan) * 32;       \
        unsigned short* _l = &B_lds[(t1) & 1][pan][wave * 512];       \
        gload_lds16(_g, _l);                                          \
        gload_lds16(_g + (size_t)128 * DIM, _l + 4096);               \
    } while (0)

    floatx4 acc[8][4];
#pragma unroll
    for (int i = 0; i < 8; ++i)
#pragma unroll
        for (int j = 0; j < 4; ++j) acc[i][j] = (floatx4)(0.0f);

    short8 a[4][2], bA[2][2], bB[2][2];

    STG_A(0, 0); STG_A(0, 1); STG_B(0, 0); STG_B(0, 1);
    asm volatile("s_waitcnt vmcnt(0)" ::: "memory");
    __syncthreads();

    for (int t = 0; t < 16; ++t) {
        const unsigned short* A0 = &A_lds[t & 1][0][0];
        const unsigned short* A1 = &A_lds[t & 1][1][0];
        const unsigned short* B0 = &B_lds[t & 1][0][0];
        const unsigned short* B1 = &B_lds[t & 1][1][0];
        const int ar = (wm * 128 + l16) * 32 + rcol;
        const int br = (wn * 64 + l16) * 32 + rcol;

        // ---- phase A: read A(mi0-3) + B(nj0-1); stage t+1 A panels ----
#pragma unroll
        for (int mi = 0; mi < 4; ++mi) {
            a[mi][0] = *(const short8*)&A0[ar + mi * 512];
            a[mi][1] = *(const short8*)&A1[ar + mi * 512];
        }
#pragma unroll
        for (int nj = 0; nj < 2; ++nj) {
            bA[nj][0] = *(const short8*)&B0[br + nj * 512];
            bA[nj][1] = *(const short8*)&B1[br + nj * 512];
        }
        if (t < 15) { STG_A(t + 1, 0); STG_A(t + 1, 1); }
        __builtin_amdgcn_s_barrier();
        __builtin_amdgcn_s_setprio(1);
#pragma unroll
        for (int mi = 0; mi < 4; ++mi)
#pragma unroll
            for (int nj = 0; nj < 2; ++nj) {
                acc[mi][nj] = __builtin_amdgcn_mfma_f32_16x16x32_bf16(bA[nj][0], a[mi][0], acc[mi][nj], 0, 0, 0);
                acc[mi][nj] = __builtin_amdgcn_mfma_f32_16x16x32_bf16(bA[nj][1], a[mi][1], acc[mi][nj], 0, 0, 0);
            }
        __builtin_amdgcn_s_setprio(0);
        __builtin_amdgcn_s_barrier();

        // ---- phase B: read B(nj2-3); stage t+1 B panels ----
#pragma unroll
        for (int nj = 0; nj < 2; ++nj) {
            bB[nj][0] = *(const short8*)&B0[br + 1024 + nj * 512];
            bB[nj][1] = *(const short8*)&B1[br + 1024 + nj * 512];
        }
        if (t < 15) { STG_B(t + 1, 0); STG_B(t + 1, 1); }
        __builtin_amdgcn_s_barrier();
        __builtin_amdgcn_s_setprio(1);
#pragma unroll
        for (int mi = 0; mi < 4; ++mi)
#pragma unroll
            for (int nj = 0; nj < 2; ++nj) {
                acc[mi][2 + nj] = __builtin_amdgcn_mfma_f32_16x16x32_bf16(bB[nj][0], a[mi][0], acc[mi][2 + nj], 0, 0, 0);
                acc[mi][2 + nj] = __builtin_amdgcn_mfma_f32_16x16x32_bf16(bB[nj][1], a[mi][1], acc[mi][2 + nj], 0, 0, 0);
            }
        __builtin_amdgcn_s_setprio(0);
        __builtin_amdgcn_s_barrier();

        // ---- phase C: read A(mi4-7); reuse bB ----
#pragma unroll
        for (int mi = 0; mi < 4; ++mi) {
            a[mi][0] = *(const short8*)&A0[ar + 2048 + mi * 512];
            a[mi][1] = *(const short8*)&A1[ar + 2048 + mi * 512];
        }
        __builtin_amdgcn_s_barrier();
        __builtin_amdgcn_s_setprio(1);
#pragma unroll
        for (int mi = 0; mi < 4; ++mi)
#pragma unroll
            for (int nj = 0; nj < 2; ++nj) {
                acc[4 + mi][2 + nj] = __builtin_amdgcn_mfma_f32_16x16x32_bf16(bB[nj][0], a[mi][0], acc[4 + mi][2 + nj], 0, 0, 0);
                acc[4 + mi][2 + nj] = __builtin_amdgcn_mfma_f32_16x16x32_bf16(bB[nj][1], a[mi][1], acc[4 + mi][2 + nj], 0, 0, 0);
            }
        __builtin_amdgcn_s_setprio(0);
        __builtin_amdgcn_s_barrier();

        // ---- phase D: pure MFMA (reuse bA); drain ----
        __builtin_amdgcn_s_setprio(1);
#pragma unroll
        for (int mi = 0; mi < 4; ++mi)
#pragma unroll
            for (int nj = 0; nj < 2; ++nj) {
                acc[4 + mi][nj] = __builtin_amdgcn_mfma_f32_16x16x32_bf16(bA[nj][0], a[mi][0], acc[4 + mi][nj], 0, 0, 0);
                acc[4 + mi][nj] = __builtin_amdgcn_mfma_f32_16x16x32_bf16(bA[nj][1], a[mi][1], acc[4 + mi][nj], 0, 0, 0);
            }
        __builtin_amdgcn_s_setprio(0);
        if (t < 15) asm volatile("s_waitcnt vmcnt(0)" ::: "memory");
        __builtin_amdgcn_s_barrier();
    }
#undef STG_A
#undef STG_B

    // epilogue: exp(score * iqn * ikn), bf16 P store, lsum atomics
#pragma unroll
    for (int i = 0; i < 8; ++i) {
        int qrow = q0 + wm * 128 + i * 16 + l16;
        float iqn = inv_qn[qrow];
        float rs = 0.f;
#pragma unroll
        for (int j = 0; j < 4; ++j) {
            int ncol = n0 + wn * 64 + j * 16 + quad * 4;
            float4 ik = *(const float4*)&inv_kn[ncol];
            float p0 = __expf(acc[i][j][0] * iqn * ik.x);
            float p1 = __expf(acc[i][j][1] * iqn * ik.y);
            float p2 = __expf(acc[i][j][2] * iqn * ik.z);
            float p3 = __expf(acc[i][j][3] * iqn * ik.w);
            ushort4 pb;
            pb.x = f32_bf16(p0); pb.y = f32_bf16(p1);
            pb.z = f32_bf16(p2); pb.w = f32_bf16(p3);
            *(ushort4*)&P[(size_t)qrow * NK + ncol] = pb;
            rs += p0 + p1 + p2 + p3;
        }
        rs += __shfl_xor(rs, 16);
        rs += __shfl_xor(rs, 32);
        if (quad == 0) atomicAdd(&lsum[qrow], rs);
    }
}

// ---------------------------------------------------------------------------
// GEMM 2 tier-1 (R13, proven): 256x256 tile, BK=64, 8 waves, 4-phase,
// split-K z=4 (grid 256), chunked XCD swizzle, XOR LDS swizzle,
// OPERAND-SWAPPED. Epilogue now packs bf16 into part[z][q][d].
// ---------------------------------------------------------------------------
__global__ __launch_bounds__(512, 2) void ctx_gemm_st(
        const unsigned short* __restrict__ P,
        const unsigned short* __restrict__ Kt,
        unsigned short* __restrict__ part) {
    __shared__ __align__(16) unsigned short A_lds[2][2][256 * 32];
    __shared__ __align__(16) unsigned short B_lds[2][2][256 * 32];

    int bid = blockIdx.x;
    int swz = (bid & 7) * 32 + (bid >> 3);
    int z  = swz >> 6;
    int y  = (swz >> 2) & 15;
    int x  = swz & 3;
    int q0 = y * 256;
    int d0 = x * 256;
    int kbase = z * (NK / 4);

    int tid  = threadIdx.x;
    int wave = tid >> 6, lane = tid & 63;
    int wm = wave >> 2, wn = wave & 3;
    int quad = lane >> 4, l16 = lane & 15;
    int rcol = (quad ^ ((l16 >> 1) & 3)) * 8;

    int schunk = ((tid & 3) ^ ((tid >> 3) & 3)) * 8;
    const unsigned short* gA = P  + (size_t)(q0 + (tid >> 2)) * NK + kbase + schunk;
    const unsigned short* gB = Kt + (size_t)(d0 + (tid >> 2)) * NK + kbase + schunk;

#define STG_A(t1, pan)                                                \
    do {                                                              \
        const unsigned short* _g = gA + (t1) * 64 + (pan) * 32;       \
        unsigned short* _l = &A_lds[(t1) & 1][pan][wave * 512];       \
        gload_lds16(_g, _l);                                          \
        gload_lds16(_g + (size_t)128 * NK, _l + 4096);                \
    } while (0)
#define STG_B(t1, pan)                                                \
    do {                                                              \
        const unsigned short* _g = gB + (t1) * 64 + (pan) * 32;       \
        unsigned short* _l = &B_lds[(t1) & 1][pan][wave * 512];       \
        gload_lds16(_g, _l);                                          \
        gload_lds16(_g + (size_t)128 * NK, _l + 4096);                \
    } while (0)

    floatx4 acc[8][4];
#pragma unroll
    for (int i = 0; i < 8; ++i)
#pragma unroll
        for (int j = 0; j < 4; ++j) acc[i][j] = (floatx4)(0.0f);

    short8 a[4][2], bA[2][2], bB[2][2];

    STG_A(0, 0); STG_A(0, 1); STG_B(0, 0); STG_B(0, 1);
    asm volatile("s_waitcnt vmcnt(0)" ::: "memory");
    __syncthreads();

    const int NT = (NK / 4) / 64;   // 32
    for (int t = 0; t < NT; ++t) {
        const unsigned short* A0 = &A_lds[t & 1][0][0];
        const unsigned short* A1 = &A_lds[t & 1][1][0];
        const unsigned short* B0 = &B_lds[t & 1][0][0];
        const unsigned short* B1 = &B_lds[t & 1][1][0];
        const int ar = (wm * 128 + l16) * 32 + rcol;
        const int br = (wn * 64 + l16) * 32 + rcol;

        // ---- phase A ----
#pragma unroll
        for (int mi = 0; mi < 4; ++mi) {
            a[mi][0] = *(const short8*)&A0[ar + mi * 512];
            a[mi][1] = *(const short8*)&A1[ar + mi * 512];
        }
#pragma unroll
        for (int nj = 0; nj < 2; ++nj) {
            bA[nj][0] = *(const short8*)&B0[br + nj * 512];
            bA[nj][1] = *(const short8*)&B1[br + nj * 512];
        }
        if (t < NT - 1) { STG_A(t + 1, 0); STG_A(t + 1, 1); }
        __builtin_amdgcn_s_barrier();
        __builtin_amdgcn_s_setprio(1);
#pragma unroll
        for (int mi = 0; mi < 4; ++mi)
#pragma unroll
            for (int nj = 0; nj < 2; ++nj) {
                acc[mi][nj] = __builtin_amdgcn_mfma_f32_16x16x32_bf16(bA[nj][0], a[mi][0], acc[mi][nj], 0, 0, 0);
                acc[mi][nj] = __builtin_amdgcn_mfma_f32_16x16x32_bf16(bA[nj][1], a[mi][1], acc[mi][nj], 0, 0, 0);
            }
        __builtin_amdgcn_s_setprio(0);
        __builtin_amdgcn_s_barrier();

        // ---- phase B ----
#pragma unroll
        for (int nj = 0; nj < 2; ++nj) {
            bB[nj][0] = *(const short8*)&B0[br + 1024 + nj * 512];
            bB[nj][1] = *(const short8*)&B1[br + 1024 + nj * 512];
        }
        if (t < NT - 1) { STG_B(t + 1, 0); STG_B(t + 1, 1); }
        __builtin_amdgcn_s_barrier();
        __builtin_amdgcn_s_setprio(1);
#pragma unroll
        for (int mi = 0; mi < 4; ++mi)
#pragma unroll
            for (int nj = 0; nj < 2; ++nj) {
                acc[mi][2 + nj] = __builtin_amdgcn_mfma_f32_16x16x32_bf16(bB[nj][0], a[mi][0], acc[mi][2 + nj], 0, 0, 0);
                acc[mi][2 + nj] = __builtin_amdgcn_mfma_f32_16x16x32_bf16(bB[nj][1], a[mi][1], acc[mi][2 + nj], 0, 0, 0);
            }
        __builtin_amdgcn_s_setprio(0);
        __builtin_amdgcn_s_barrier();

        // ---- phase C ----
#pragma unroll
        for (int mi = 0; mi < 4; ++mi) {
            a[mi][0] = *(const short8*)&A0[ar + 2048 + mi * 512];
            a[mi][1] = *(const short8*)&A1[ar + 2048 + mi * 512];
        }
        __builtin_amdgcn_s_barrier();
        __builtin_amdgcn_s_setprio(1);
#pragma unroll
        for (int mi = 0; mi < 4; ++mi)
#pragma unroll
            for (int nj = 0; nj < 2; ++nj) {
                acc[4 + mi][2 + nj] = __builtin_amdgcn_mfma_f32_16x16x32_bf16(bB[nj][0], a[mi][0], acc[4 + mi][2 + nj], 0, 0, 0);
                acc[4 + mi][2 + nj] = __builtin_amdgcn_mfma_f32_16x16x32_bf16(bB[nj][1], a[mi][1], acc[4 + mi][2 + nj], 0, 0, 0);
            }
        __builtin_amdgcn_s_setprio(0);
        __builtin_amdgcn_s_barrier();

        // ---- phase D ----
        __builtin_amdgcn_s_setprio(1);
#pragma unroll
        for (int mi = 0; mi < 4; ++mi)
#pragma unroll
            for (int nj = 0; nj < 2; ++nj) {
                acc[4 + mi][nj] = __builtin_amdgcn_mfma_f32_16x16x32_bf16(bA[nj][0], a[mi][0], acc[4 + mi][nj], 0, 0, 0);
                acc[4 + mi][nj] = __builtin_amdgcn_mfma_f32_16x16x32_bf16(bA[nj][1], a[mi][1], acc[4 + mi][nj], 0, 0, 0);
            }
        __builtin_amdgcn_s_setprio(0);
        if (t < NT - 1) asm volatile("s_waitcnt vmcnt(0)" ::: "memory");
        __builtin_amdgcn_s_barrier();
    }
#undef STG_A
#undef STG_B

    // epilogue: swapped layout -> acc[i][j] lane(quad,l16) reg r =
    // C[q = i*16+l16][d = j*16+quad*4+r]; bf16-packed partial stores.
    unsigned short* pslice = part + (size_t)z * NQ * DIM;
#pragma unroll
    for (int i = 0; i < 8; ++i) {
        int qrow = q0 + wm * 128 + i * 16 + l16;
#pragma unroll
        for (int j = 0; j < 4; ++j) {
            int dcol = d0 + wn * 64 + j * 16 + quad * 4;
            ushort4 v;
            v.x = f32_bf16(acc[i][j][0]); v.y = f32_bf16(acc[i][j][1]);
            v.z = f32_bf16(acc[i][j][2]); v.w = f32_bf16(acc[i][j][3]);
            *(ushort4*)&pslice[(size_t)qrow * DIM + dcol] = v;
        }
    }
}

// ---------------------------------------------------------------------------
// reduce: out[q][d] = (sum_z bf16 part[z][q][d]) / lsum[q]
// ---------------------------------------------------------------------------
__global__ void reduce_out(const unsigned short* __restrict__ part,
                           const float* __restrict__ lsum,
                           float* __restrict__ out) {
    size_t idx = ((size_t)blockIdx.x * 256 + threadIdx.x) * 4;
    int q = (int)(idx >> 10);
    float inv = 1.0f / lsum[q];
    const size_t S = (size_t)NQ * DIM;
    ushort4 a0 = *(const ushort4*)(part + idx);
    ushort4 a1 = *(const ushort4*)(part + S + idx);
    ushort4 a2 = *(const ushort4*)(part + 2 * S + idx);
    ushort4 a3 = *(const ushort4*)(part + 3 * S + idx);
    float4 o;
    o.x = (bf16_f32(a0.x) + bf16_f32(a1.x) + bf16_f32(a2.x) + bf16_f32(a3.x)) * inv;
    o.y = (bf16_f32(a0.y) + bf16_f32(a1.y) + bf16_f32(a2.y) + bf16_f32(a3.y)) * inv;
    o.z = (bf16_f32(a0.z) + bf16_f32(a1.z) + bf16_f32(a2.z) + bf16_f32(a3.z)) * inv;
    o.w = (bf16_f32(a0.w) + bf16_f32(a1.w) + bf16_f32(a2.w) + bf16_f32(a3.w)) * inv;
    *(float4*)(out + idx) = o;
}

// ---------------------------------------------------------------------------
// GEMM 2 tier-2 (exact R10): atomics into pre-zeroed out.
// ---------------------------------------------------------------------------
__global__ void ctx_gemm(const unsigned short* __restrict__ P,
                         const unsigned short* __restrict__ Kt,
                         const float* __restrict__ lsum,
                         float* __restrict__ out) {
    __shared__ __align__(16) unsigned short As[128 * 32];
    __shared__ __align__(16) unsigned short Bs[128 * 32];
    int id = blockIdx.x;
    int r8 = id & 7;
    int t  = id >> 3;
    int x  = t & 7;
    int g  = ((t >> 3) << 3) | r8;
    int y  = g & 31;
    int z  = g >> 5;
    int q0 = y * 128;
    int d0 = x * 128;
    int kbase = z * (NK / 4);

    int tid = threadIdx.x;
    int wave = tid >> 6, lane = tid & 63;
    int wm = wave >> 1, wn = wave & 1;
    int quad = lane >> 4, l16 = lane & 15;

    int srow   = wave * 32 + (lane >> 2);
    int schunk = (((lane & 3) ^ ((lane >> 3) & 3))) * 8;
    const unsigned short* gA0 = P + (size_t)(q0 + srow) * NK + kbase + schunk;
    const unsigned short* gA1 = gA0 + (size_t)16 * NK;
    const unsigned short* gB0 = Kt + (size_t)(d0 + srow) * NK + kbase + schunk;
    const unsigned short* gB1 = gB0 + (size_t)16 * NK;
    unsigned short* lA0 = As + wave * 32 * 32;
    unsigned short* lA1 = lA0 + 16 * 32;
    unsigned short* lB0 = Bs + wave * 32 * 32;
    unsigned short* lB1 = lB0 + 16 * 32;

    int rcol = (quad ^ ((l16 >> 1) & 3)) * 8;

    floatx4 acc[4][4];
#pragma unroll
    for (int i = 0; i < 4; ++i)
#pragma unroll
        for (int j = 0; j < 4; ++j) acc[i][j] = (floatx4)(0.0f);

    for (int kb = 0; kb < (NK / 4) / 32; ++kb) {
        int k0 = kb * 32;
        __syncthreads();
        gload_lds16(gA0 + k0, lA0);
        gload_lds16(gA1 + k0, lA1);
        gload_lds16(gB0 + k0, lB0);
        gload_lds16(gB1 + k0, lB1);
        __syncthreads();
        short8 a[4], b[4];
#pragma unroll
        for (int i = 0; i < 4; ++i)
            a[i] = *(const short8*)&As[(wm * 64 + i * 16 + l16) * 32 + rcol];
#pragma unroll
        for (int j = 0; j < 4; ++j)
            b[j] = *(const short8*)&Bs[(wn * 64 + j * 16 + l16) * 32 + rcol];
#pragma unroll
        for (int i = 0; i < 4; ++i)
#pragma unroll
            for (int j = 0; j < 4; ++j)
                acc[i][j] = __builtin_amdgcn_mfma_f32_16x16x32_bf16(a[i], b[j], acc[i][j], 0, 0, 0);
    }

#pragma unroll
    for (int i = 0; i < 4; ++i) {
        float invl[4];
#pragma unroll
        for (int r = 0; r < 4; ++r)
            invl[r] = 1.0f / lsum[q0 + wm * 64 + i * 16 + quad * 4 + r];
#pragma unroll
        for (int j = 0; j < 4; ++j) {
#pragma unroll
            for (int r = 0; r < 4; ++r) {
                int qrow = q0 + wm * 64 + i * 16 + quad * 4 + r;
                int dcol = d0 + wn * 64 + j * 16 + l16;
                atomicAdd(&out[(size_t)qrow * DIM + dcol], acc[i][j][r] * invl[r]);
            }
        }
    }
}

// ---------------------------------------------------------------------------
// Path D fallback (ws too small) — correct but slow.
// ---------------------------------------------------------------------------
__global__ void fused_fallback(const float* __restrict__ Q,
                               const float* __restrict__ K,
                               float* __restrict__ out) {
    int wave = threadIdx.x >> 6, lane = threadIdx.x & 63;
    int q0 = blockIdx.x * 16 + wave * 4;
    float qv[4][16], acc[4][16], iqn[4], ls[4];
#pragma unroll
    for (int r = 0; r < 4; ++r) {
        float s = 0.f;
#pragma unroll
        for (int c = 0; c < 4; ++c) {
            float4 f = *(const float4*)(Q + (size_t)(q0 + r) * DIM + c * 256 + lane * 4);
            qv[r][c * 4 + 0] = f.x; qv[r][c * 4 + 1] = f.y;
            qv[r][c * 4 + 2] = f.z; qv[r][c * 4 + 3] = f.w;
            s += f.x * f.x + f.y * f.y + f.z * f.z + f.w * f.w;
        }
#pragma unroll
        for (int off = 32; off > 0; off >>= 1) s += __shfl_xor(s, off);
        iqn[r] = 1.0f / sqrtf(s);
        ls[r] = 0.f;
#pragma unroll
        for (int t = 0; t < 16; ++t) acc[r][t] = 0.f;
    }
    for (int k = 0; k < NK; ++k) {
        const float* kr = K + (size_t)k * DIM;
        float kv[16], ss = 0.f;
#pragma unroll
        for (int c = 0; c < 4; ++c) {
            float4 f = *(const float4*)(kr + c * 256 + lane * 4);
            kv[c * 4 + 0] = f.x; kv[c * 4 + 1] = f.y;
            kv[c * 4 + 2] = f.z; kv[c * 4 + 3] = f.w;
            ss += f.x * f.x + f.y * f.y + f.z * f.z + f.w * f.w;
        }
        float d0 = 0.f, d1 = 0.f, d2 = 0.f, d3 = 0.f;
#pragma unroll
        for (int t = 0; t < 16; ++t) {
            d0 += qv[0][t] * kv[t]; d1 += qv[1][t] * kv[t];
            d2 += qv[2][t] * kv[t]; d3 += qv[3][t] * kv[t];
        }
#pragma unroll
        for (int off = 32; off > 0; off >>= 1) {
            ss += __shfl_xor(ss, off);
            d0 += __shfl_xor(d0, off); d1 += __shfl_xor(d1, off);
            d2 += __shfl_xor(d2, off); d3 += __shfl_xor(d3, off);
        }
        float ikn = 1.0f / sqrtf(ss);
        float p0 = __expf(d0 * iqn[0] * ikn), p1 = __expf(d1 * iqn[1] * ikn);
        float p2 = __expf(d2 * iqn[2] * ikn), p3 = __expf(d3 * iqn[3] * ikn);
        ls[0] += p0; ls[1] += p1; ls[2] += p2; ls[3] += p3;
#pragma unroll
        for (int t = 0; t < 16; ++t) {
            acc[0][t] += p0 * kv[t]; acc[1][t] += p1 * kv[t];
            acc[2][t] += p2 * kv[t]; acc[3][t] += p3 * kv[t];
        }
    }
#pragma unroll
    for (int r = 0; r < 4; ++r) {
        float inv = 1.0f / ls[r];
#pragma unroll
        for (int c = 0; c < 4; ++c) {
            float4 o;
            o.x = acc[r][c * 4 + 0] * inv; o.y = acc[r][c * 4 + 1] * inv;
            o.z = acc[r][c * 4 + 2] * inv; o.w = acc[r][c * 4 + 3] * inv;
            *(float4*)(out + (size_t)(q0 + r) * DIM + c * 256 + lane * 4) = o;
        }
    }
}

// ---------------------------------------------------------------------------
// launch — tiers:
//  T1 (ws>=152M+64K): Qb[0,8M) Kb[8,24M) P[24,88M) part_bf16[88,120M)
//                     Kt[120,136M) scalars @152M; prep_all + transpose_bf16
//                     + score + ctx_gemm_st + reduce_out.
//  T2 (ws>=88M+64K):  legacy aliased layout (Kt@0 after score), atomics.
//  else: fallback.
// ---------------------------------------------------------------------------
extern "C" void kernel_launch(void* const* d_in, const int* in_sizes, int n_in,
                              void* d_out, int out_size, void* d_ws, size_t ws_size,
                              hipStream_t stream) {
    const float* Q = (const float*)d_in[0];
    const float* K = (const float*)d_in[1];
    float* out = (float*)d_out;
    char* ws = (char*)d_ws;

    const size_t REQ_T1 = ((size_t)152u << 20) + 65536;
    const size_t REQ_T2 = ((size_t)88u << 20) + 65536;

    if (ws_size >= REQ_T1) {
        unsigned short* Qb = (unsigned short*)(ws);
        unsigned short* Kb = (unsigned short*)(ws + (size_t)(8u << 20));
        unsigned short* P  = (unsigned short*)(ws + (size_t)(24u << 20));
        unsigned short* part = (unsigned short*)(ws + (size_t)(88u << 20));
        unsigned short* Kt = (unsigned short*)(ws + (size_t)(120u << 20));
        float* inv_qn = (float*)(ws + (size_t)(152u << 20));
        float* inv_kn = (float*)(ws + (size_t)(152u << 20) + 16384);
        float* lsum   = (float*)(ws + (size_t)(152u << 20) + 49152);

        prep_all<<<NQ / 4 + NK / 4, 256, 0, stream>>>(Q, K, Qb, Kb, inv_qn, inv_kn, lsum, nullptr);
        transpose_bf16<<<dim3(NK / 64, DIM / 64), 256, 0, stream>>>(Kb, Kt);
        score_gemm<<<512, 512, 0, stream>>>(Qb, Kb, inv_qn, inv_kn, P, lsum);
        ctx_gemm_st<<<256, 512, 0, stream>>>(P, Kt, part);
        reduce_out<<<NQ * DIM / 1024, 256, 0, stream>>>(part, lsum, out);
    } else if (ws_size >= REQ_T2) {
        unsigned short* Kt = (unsigned short*)(ws);
        unsigned short* Qb = (unsigned short*)(ws);
        unsigned short* Kb = (unsigned short*)(ws + (size_t)(8u << 20));
        unsigned short* P  = (unsigned short*)(ws + (size_t)(24u << 20));
        float* inv_qn = (float*)(ws + (size_t)(88u << 20));
        float* inv_kn = (float*)(ws + (size_t)(88u << 20) + 16384);
        float* lsum   = (float*)(ws + (size_t)(88u << 20) + 49152);

        prep_all<<<NQ / 4 + NK / 4, 256, 0, stream>>>(Q, K, Qb, Kb, inv_qn, inv_kn, lsum, out);
        score_gemm<<<512, 512, 0, stream>>>(Qb, Kb, inv_qn, inv_kn, P, lsum);
        transpose_cvt<<<dim3(NK / 64, DIM / 64), 256, 0, stream>>>(K, Kt);
        ctx_gemm<<<1024, 256, 0, stream>>>(P, Kt, lsum, out);
    } else {
        fused_fallback<<<NQ / 16, 256, 0, stream>>>(Q, K, out);
    }
}

// Round 9
// 240.975 us; speedup vs baseline: 1.1180x; 1.0338x over previous
//
// R20: R19 + (1) L2-fitting sub-group block remap in both GEMMs (score:
// 4qx4n groups per XCD, ctx: 2yx2x groups — working set fits 4 MB L2,
// attacks the 3x FETCH overfetch), (2) setprio removed (m190: negative on
// non-8-phase GEMM). Everything else identical to R19.
#include <hip/hip_runtime.h>

#define NQ 4096
#define NK 8192
#define DIM 1024

typedef __attribute__((ext_vector_type(8))) short short8;
typedef __attribute__((ext_vector_type(4))) float floatx4;
typedef unsigned int u32;
typedef __attribute__((address_space(3))) u32 lds_u32;
typedef __attribute__((address_space(1))) const u32 glb_u32;

__device__ __forceinline__ void gload_lds16(const void* g, void* l) {
    __builtin_amdgcn_global_load_lds((glb_u32*)g, (lds_u32*)l, 16, 0, 0);
}

__device__ __forceinline__ unsigned short f32_bf16(float f) {
    unsigned int u = __float_as_uint(f);
    u += 0x7fff + ((u >> 16) & 1);
    return (unsigned short)(u >> 16);
}

__device__ __forceinline__ float bf16_f32(unsigned short u) {
    return __uint_as_float((u32)u << 16);
}

// ---------------------------------------------------------------------------
// prep_all: blocks [0,NQ/4) process Q rows (+ optional zero(out) + zero lsum),
// blocks [NQ/4, NQ/4+NK/4) process K rows. bf16 convert + 1/norm.
// ---------------------------------------------------------------------------
__global__ void prep_all(const float* __restrict__ Q,
                         const float* __restrict__ K,
                         unsigned short* __restrict__ Qb,
                         unsigned short* __restrict__ Kb,
                         float* __restrict__ inv_qn,
                         float* __restrict__ inv_kn,
                         float* __restrict__ lsum,
                         float* __restrict__ out_zero) {
    int wave = threadIdx.x >> 6;
    int lane = threadIdx.x & 63;
    int bid  = blockIdx.x;
    const float* src;
    unsigned short* dst;
    float* invp;
    int row;
    if (bid < NQ / 4) {
        row = bid * 4 + wave; src = Q; dst = Qb; invp = inv_qn;
    } else {
        row = (bid - NQ / 4) * 4 + wave; src = K; dst = Kb; invp = inv_kn;
    }
    const float* r = src + (size_t)row * DIM;
    float s = 0.f;
#pragma unroll
    for (int c = 0; c < 4; ++c) {
        float4 f = *(const float4*)(r + c * 256 + lane * 4);
        s += f.x * f.x + f.y * f.y + f.z * f.z + f.w * f.w;
        ushort4 b;
        b.x = f32_bf16(f.x); b.y = f32_bf16(f.y);
        b.z = f32_bf16(f.z); b.w = f32_bf16(f.w);
        *(ushort4*)(dst + (size_t)row * DIM + c * 256 + lane * 4) = b;
    }
#pragma unroll
    for (int off = 32; off > 0; off >>= 1) s += __shfl_xor(s, off);
    if (lane == 0) invp[row] = 1.0f / sqrtf(s);

    if (bid < NQ / 4) {
        float4 z = make_float4(0.f, 0.f, 0.f, 0.f);
        if (out_zero) {
#pragma unroll
            for (int c = 0; c < 4; ++c)
                *(float4*)(out_zero + (size_t)bid * 4096 + c * 1024 + threadIdx.x * 4) = z;
        }
        if (bid < 4)
            *(float4*)(lsum + bid * 1024 + threadIdx.x * 4) = z;
    }
}

// ---------------------------------------------------------------------------
// transpose (bf16 -> bf16): Kt[d][kn] = Kb[kn][d]   (T1 path)
// ---------------------------------------------------------------------------
__global__ void transpose_bf16(const unsigned short* __restrict__ Kb,
                               unsigned short* __restrict__ Kt) {
    __shared__ unsigned short t[64][66];
    int kn0 = blockIdx.x * 64, d0 = blockIdx.y * 64;
    int tid = threadIdx.x;
    int r  = tid >> 4;
    int c4 = (tid & 15) * 4;
#pragma unroll
    for (int s = 0; s < 4; ++s) {
        int kk = s * 16 + r;
        ushort4 v = *(const ushort4*)(Kb + (size_t)(kn0 + kk) * DIM + d0 + c4);
        t[kk][c4 + 0] = v.x; t[kk][c4 + 1] = v.y;
        t[kk][c4 + 2] = v.z; t[kk][c4 + 3] = v.w;
    }
    __syncthreads();
#pragma unroll
    for (int s = 0; s < 4; ++s) {
        int dd = s * 16 + r;
        ushort4 b;
        b.x = t[c4 + 0][dd]; b.y = t[c4 + 1][dd];
        b.z = t[c4 + 2][dd]; b.w = t[c4 + 3][dd];
        *(ushort4*)(Kt + (size_t)(d0 + dd) * NK + kn0 + c4) = b;
    }
}

// ---------------------------------------------------------------------------
// transpose + convert (f32 -> bf16): Kt[d][kn] = bf16(K[kn][d])  (T2 legacy)
// ---------------------------------------------------------------------------
__global__ void transpose_cvt(const float* __restrict__ K,
                              unsigned short* __restrict__ Kt) {
    __shared__ float t[64][65];
    int kn0 = blockIdx.x * 64, d0 = blockIdx.y * 64;
    int tid = threadIdx.x;
    int r  = tid >> 4;
    int c4 = (tid & 15) * 4;
#pragma unroll
    for (int s = 0; s < 4; ++s) {
        int kk = s * 16 + r;
        float4 f = *(const float4*)(K + (size_t)(kn0 + kk) * DIM + d0 + c4);
        t[kk][c4 + 0] = f.x; t[kk][c4 + 1] = f.y;
        t[kk][c4 + 2] = f.z; t[kk][c4 + 3] = f.w;
    }
    __syncthreads();
#pragma unroll
    for (int s = 0; s < 4; ++s) {
        int dd = s * 16 + r;
        ushort4 b;
        b.x = f32_bf16(t[c4 + 0][dd]);
        b.y = f32_bf16(t[c4 + 1][dd]);
        b.z = f32_bf16(t[c4 + 2][dd]);
        b.w = f32_bf16(t[c4 + 3][dd]);
        *(ushort4*)(Kt + (size_t)(d0 + dd) * NK + kn0 + c4) = b;
    }
}

// ---------------------------------------------------------------------------
// GEMM 1: 256x256 tile, BK=64, 8 waves, 4 phases/K-tile, raw s_barrier +
// vmcnt(0) drain once per tile, XOR swizzle. R20: L2-group remap — XCD c
// handles n-tiles 4c..4c+3; 16-block groups cover 4q x 4n (L2-fit).
// Epilogue: exp + bf16 P store + lsum atomics.
// ---------------------------------------------------------------------------
__global__ __launch_bounds__(512, 2) void score_gemm(
        const unsigned short* __restrict__ Qb,
        const unsigned short* __restrict__ Kb,
        const float* __restrict__ inv_qn,
        const float* __restrict__ inv_kn,
        unsigned short* __restrict__ P,
        float* __restrict__ lsum) {
    __shared__ __align__(16) unsigned short A_lds[2][2][256 * 32];
    __shared__ __align__(16) unsigned short B_lds[2][2][256 * 32];

    // bijective remap: xcd = bid&7, local = bid>>3 in [0,64):
    //   group g = local>>4 (4 q-tiles), w = local&15:
    //   q = g*4 + (w&3), n = xcd*4 + (w>>2). Working set 2+2 MB = L2-fit.
    int bid  = blockIdx.x;
    int xcd  = bid & 7;
    int loc  = bid >> 3;
    int g    = loc >> 4;
    int w    = loc & 15;
    int q0   = (g * 4 + (w & 3)) * 256;
    int n0   = (xcd * 4 + (w >> 2)) * 256;

    int tid  = threadIdx.x;
    int wave = tid >> 6, lane = tid & 63;
    int wm = wave >> 2, wn = wave & 3;       // 2 x 4 wave grid
    int quad = lane >> 4, l16 = lane & 15;
    int rcol = (quad ^ ((l16 >> 1) & 3)) * 8;

    int schunk = ((tid & 3) ^ ((tid >> 3) & 3)) * 8;
    const unsigned short* gA = Qb + (size_t)(q0 + (tid >> 2)) * DIM + schunk;
    const unsigned short* gB = Kb + (size_t)(n0 + (tid >> 2)) * DIM + schunk;

#define STG_A(t1, pan)                                                \
    do {                                                              \
        const unsigned short* _g = gA + (t1) * 64 + (pan) * 32;       \
        unsigned short* _l = &A_lds[(t1) & 1][pan][wave * 512];       \
        gload_lds16(_g, _l);                                          \
        gload_lds16(_g + (size_t)128 * DIM, _l + 4096);               \
    } while (0)
#define STG_B(t1, pan)                                                \
    do {                                                              \
        const unsigned short* _g = gB + (t1) * 64 + (pan) * 32;       \
        unsigned short* _l = &B_lds[(t1) & 1][pan][wave * 512];       \
        gload_lds16(_g, _l);                                          \
        gload_lds16(_g + (size_t)128 * DIM, _l + 4096);               \
    } while (0)

    floatx4 acc[8][4];
#pragma unroll
    for (int i = 0; i < 8; ++i)
#pragma unroll
        for (int j = 0; j < 4; ++j) acc[i][j] = (floatx4)(0.0f);

    short8 a[4][2], bA[2][2], bB[2][2];

    STG_A(0, 0); STG_A(0, 1); STG_B(0, 0); STG_B(0, 1);
    asm volatile("s_waitcnt vmcnt(0)" ::: "memory");
    __syncthreads();

    for (int t = 0; t < 16; ++t) {
        const unsigned short* A0 = &A_lds[t & 1][0][0];
        const unsigned short* A1 = &A_lds[t & 1][1][0];
        const unsigned short* B0 = &B_lds[t & 1][0][0];
        const unsigned short* B1 = &B_lds[t & 1][1][0];
        const int ar = (wm * 128 + l16) * 32 + rcol;
        const int br = (wn * 64 + l16) * 32 + rcol;

        // ---- phase A: read A(mi0-3) + B(nj0-1); stage t+1 A panels ----
#pragma unroll
        for (int mi = 0; mi < 4; ++mi) {
            a[mi][0] = *(const short8*)&A0[ar + mi * 512];
            a[mi][1] = *(const short8*)&A1[ar + mi * 512];
        }
#pragma unroll
        for (int nj = 0; nj < 2; ++nj) {
            bA[nj][0] = *(const short8*)&B0[br + nj * 512];
            bA[nj][1] = *(const short8*)&B1[br + nj * 512];
        }
        if (t < 15) { STG_A(t + 1, 0); STG_A(t + 1, 1); }
        __builtin_amdgcn_s_barrier();
#pragma unroll
        for (int mi = 0; mi < 4; ++mi)
#pragma unroll
            for (int nj = 0; nj < 2; ++nj) {
                acc[mi][nj] = __builtin_amdgcn_mfma_f32_16x16x32_bf16(bA[nj][0], a[mi][0], acc[mi][nj], 0, 0, 0);
                acc[mi][nj] = __builtin_amdgcn_mfma_f32_16x16x32_bf16(bA[nj][1], a[mi][1], acc[mi][nj], 0, 0, 0);
            }
        __builtin_amdgcn_s_barrier();

        // ---- phase B: read B(nj2-3); stage t+1 B panels ----
#pragma unroll
        for (int nj = 0; nj < 2; ++nj) {
            bB[nj][0] = *(const short8*)&B0[br + 1024 + nj * 512];
            bB[nj][1] = *(const short8*)&B1[br + 1024 + nj * 512];
        }
        if (t < 15) { STG_B(t + 1, 0); STG_B(t + 1, 1); }
        __builtin_amdgcn_s_barrier();
#pragma unroll
        for (int mi = 0; mi < 4; ++mi)
#pragma unroll
            for (int nj = 0; nj < 2; ++nj) {
                acc[mi][2 + nj] = __builtin_amdgcn_mfma_f32_16x16x32_bf16(bB[nj][0], a[mi][0], acc[mi][2 + nj], 0, 0, 0);
                acc[mi][2 + nj] = __builtin_amdgcn_mfma_f32_16x16x32_bf16(bB[nj][1], a[mi][1], acc[mi][2 + nj], 0, 0, 0);
            }
        __builtin_amdgcn_s_barrier();

        // ---- phase C: read A(mi4-7); reuse bB ----
#pragma unroll
        for (int mi = 0; mi < 4; ++mi) {
            a[mi][0] = *(const short8*)&A0[ar + 2048 + mi * 512];
            a[mi][1] = *(const short8*)&A1[ar + 2048 + mi * 512];
        }
        __builtin_amdgcn_s_barrier();
#pragma unroll
        for (int mi = 0; mi < 4; ++mi)
#pragma unroll
            for (int nj = 0; nj < 2; ++nj) {
                acc[4 + mi][2 + nj] = __builtin_amdgcn_mfma_f32_16x16x32_bf16(bB[nj][0], a[mi][0], acc[4 + mi][2 + nj], 0, 0, 0);
                acc[4 + mi][2 + nj] = __builtin_amdgcn_mfma_f32_16x16x32_bf16(bB[nj][1], a[mi][1], acc[4 + mi][2 + nj], 0, 0, 0);
            }
        __builtin_amdgcn_s_barrier();

        // ---- phase D: pure MFMA (reuse bA); drain ----
#pragma unroll
        for (int mi = 0; mi < 4; ++mi)
#pragma unroll
            for (int nj = 0; nj < 2; ++nj) {
                acc[4 + mi][nj] = __builtin_amdgcn_mfma_f32_16x16x32_bf16(bA[nj][0], a[mi][0], acc[4 + mi][nj], 0, 0, 0);
                acc[4 + mi][nj] = __builtin_amdgcn_mfma_f32_16x16x32_bf16(bA[nj][1], a[mi][1], acc[4 + mi][nj], 0, 0, 0);
            }
        if (t < 15) asm volatile("s_waitcnt vmcnt(0)" ::: "memory");
        __builtin_amdgcn_s_barrier();
    }
#undef STG_A
#undef STG_B

    // epilogue: exp(score * iqn * ikn), bf16 P store, lsum atomics
#pragma unroll
    for (int i = 0; i < 8; ++i) {
        int qrow = q0 + wm * 128 + i * 16 + l16;
        float iqn = inv_qn[qrow];
        float rs = 0.f;
#pragma unroll
        for (int j = 0; j < 4; ++j) {
            int ncol = n0 + wn * 64 + j * 16 + quad * 4;
            float4 ik = *(const float4*)&inv_kn[ncol];
            float p0 = __expf(acc[i][j][0] * iqn * ik.x);
            float p1 = __expf(acc[i][j][1] * iqn * ik.y);
            float p2 = __expf(acc[i][j][2] * iqn * ik.z);
            float p3 = __expf(acc[i][j][3] * iqn * ik.w);
            ushort4 pb;
            pb.x = f32_bf16(p0); pb.y = f32_bf16(p1);
            pb.z = f32_bf16(p2); pb.w = f32_bf16(p3);
            *(ushort4*)&P[(size_t)qrow * NK + ncol] = pb;
            rs += p0 + p1 + p2 + p3;
        }
        rs += __shfl_xor(rs, 16);
        rs += __shfl_xor(rs, 32);
        if (quad == 0) atomicAdd(&lsum[qrow], rs);
    }
}

// ---------------------------------------------------------------------------
// GEMM 2 tier-1: 256x256 tile, BK=64, 8 waves, 4-phase, split-K z=4 (grid
// 256), XOR LDS swizzle, OPERAND-SWAPPED, bf16 part stores. R20: L2-group
// remap — XCD c: z=c>>1, y in [ (c&1)*8, +8 ), 4-block groups cover 2y x 2x.
// ---------------------------------------------------------------------------
__global__ __launch_bounds__(512, 2) void ctx_gemm_st(
        const unsigned short* __restrict__ P,
        const unsigned short* __restrict__ Kt,
        unsigned short* __restrict__ part) {
    __shared__ __align__(16) unsigned short A_lds[2][2][256 * 32];
    __shared__ __align__(16) unsigned short B_lds[2][2][256 * 32];

    // bijective remap: xcd = bid&7, local = bid>>3 in [0,32):
    //   z = xcd>>1, p = xcd&1; grp = local>>2: yg = grp>>1, xg = grp&1;
    //   w = local&3: y = p*8 + yg*2 + (w&1), x = xg*2 + (w>>1).
    int bid = blockIdx.x;
    int xcd = bid & 7;
    int loc = bid >> 3;
    int z   = xcd >> 1;
    int pty = xcd & 1;
    int grp = loc >> 2;
    int w   = loc & 3;
    int y   = pty * 8 + (grp >> 1) * 2 + (w & 1);
    int x   = (grp & 1) * 2 + (w >> 1);
    int q0 = y * 256;
    int d0 = x * 256;
    int kbase = z * (NK / 4);

    int tid  = threadIdx.x;
    int wave = tid >> 6, lane = tid & 63;
    int wm = wave >> 2, wn = wave & 3;
    int quad = lane >> 4, l16 = lane & 15;
    int rcol = (quad ^ ((l16 >> 1) & 3)) * 8;

    int schunk = ((tid & 3) ^ ((tid >> 3) & 3)) * 8;
    const unsigned short* gA = P  + (size_t)(q0 + (tid >> 2)) * NK + kbase + schunk;
    const unsigned short* gB = Kt + (size_t)(d0 + (tid >> 2)) * NK + kbase + schunk;

#define STG_A(t1, pan)                                                \
    do {                                                              \
        const unsigned short* _g = gA + (t1) * 64 + (pan) * 32;       \
        unsigned short* _l = &A_lds[(t1) & 1][pan][wave * 512];       \
        gload_lds16(_g, _l);                                          \
        gload_lds16(_g + (size_t)128 * NK, _l + 4096);                \
    } while (0)
#define STG_B(t1, pan)                                                \
    do {                                                              \
        const unsigned short* _g = gB + (t1) * 64 + (pan) * 32;       \
        unsigned short* _l = &B_lds[(t1) & 1][pan][wave * 512];       \
        gload_lds16(_g, _l);                                          \
        gload_lds16(_g + (size_t)128 * NK, _l + 4096);                \
    } while (0)

    floatx4 acc[8][4];
#pragma unroll
    for (int i = 0; i < 8; ++i)
#pragma unroll
        for (int j = 0; j < 4; ++j) acc[i][j] = (floatx4)(0.0f);

    short8 a[4][2], bA[2][2], bB[2][2];

    STG_A(0, 0); STG_A(0, 1); STG_B(0, 0); STG_B(0, 1);
    asm volatile("s_waitcnt vmcnt(0)" ::: "memory");
    __syncthreads();

    const int NT = (NK / 4) / 64;   // 32
    for (int t = 0; t < NT; ++t) {
        const unsigned short* A0 = &A_lds[t & 1][0][0];
        const unsigned short* A1 = &A_lds[t & 1][1][0];
        const unsigned short* B0 = &B_lds[t & 1][0][0];
        const unsigned short* B1 = &B_lds[t & 1][1][0];
        const int ar = (wm * 128 + l16) * 32 + rcol;
        const int br = (wn * 64 + l16) * 32 + rcol;

        // ---- phase A ----
#pragma unroll
        for (int mi = 0; mi < 4; ++mi) {
            a[mi][0] = *(const short8*)&A0[ar + mi * 512];
            a[mi][1] = *(const short8*)&A1[ar + mi * 512];
        }
#pragma unroll
        for (int nj = 0; nj < 2; ++nj) {
            bA[nj][0] = *(const short8*)&B0[br + nj * 512];
            bA[nj][1] = *(const short8*)&B1[br + nj * 512];
        }
        if (t < NT - 1) { STG_A(t + 1, 0); STG_A(t + 1, 1); }
        __builtin_amdgcn_s_barrier();
#pragma unroll
        for (int mi = 0; mi < 4; ++mi)
#pragma unroll
            for (int nj = 0; nj < 2; ++nj) {
                acc[mi][nj] = __builtin_amdgcn_mfma_f32_16x16x32_bf16(bA[nj][0], a[mi][0], acc[mi][nj], 0, 0, 0);
                acc[mi][nj] = __builtin_amdgcn_mfma_f32_16x16x32_bf16(bA[nj][1], a[mi][1], acc[mi][nj], 0, 0, 0);
            }
        __builtin_amdgcn_s_barrier();

        // ---- phase B ----
#pragma unroll
        for (int nj = 0; nj < 2; ++nj) {
            bB[nj][0] = *(const short8*)&B0[br + 1024 + nj * 512];
            bB[nj][1] = *(const short8*)&B1[br + 1024 + nj * 512];
        }
        if (t < NT - 1) { STG_B(t + 1, 0); STG_B(t + 1, 1); }
        __builtin_amdgcn_s_barrier();
#pragma unroll
        for (int mi = 0; mi < 4; ++mi)
#pragma unroll
            for (int nj = 0; nj < 2; ++nj) {
                acc[mi][2 + nj] = __builtin_amdgcn_mfma_f32_16x16x32_bf16(bB[nj][0], a[mi][0], acc[mi][2 + nj], 0, 0, 0);
                acc[mi][2 + nj] = __builtin_amdgcn_mfma_f32_16x16x32_bf16(bB[nj][1], a[mi][1], acc[mi][2 + nj], 0, 0, 0);
            }
        __builtin_amdgcn_s_barrier();

        // ---- phase C ----
#pragma unroll
        for (int mi = 0; mi < 4; ++mi) {
            a[mi][0] = *(const short8*)&A0[ar + 2048 + mi * 512];
            a[mi][1] = *(const short8*)&A1[ar + 2048 + mi * 512];
        }
        __builtin_amdgcn_s_barrier();
#pragma unroll
        for (int mi = 0; mi < 4; ++mi)
#pragma unroll
            for (int nj = 0; nj < 2; ++nj) {
                acc[4 + mi][2 + nj] = __builtin_amdgcn_mfma_f32_16x16x32_bf16(bB[nj][0], a[mi][0], acc[4 + mi][2 + nj], 0, 0, 0);
                acc[4 + mi][2 + nj] = __builtin_amdgcn_mfma_f32_16x16x32_bf16(bB[nj][1], a[mi][1], acc[4 + mi][2 + nj], 0, 0, 0);
            }
        __builtin_amdgcn_s_barrier();

        // ---- phase D ----
#pragma unroll
        for (int mi = 0; mi < 4; ++mi)
#pragma unroll
            for (int nj = 0; nj < 2; ++nj) {
                acc[4 + mi][nj] = __builtin_amdgcn_mfma_f32_16x16x32_bf16(bA[nj][0], a[mi][0], acc[4 + mi][nj], 0, 0, 0);
                acc[4 + mi][nj] = __builtin_amdgcn_mfma_f32_16x16x32_bf16(bA[nj][1], a[mi][1], acc[4 + mi][nj], 0, 0, 0);
            }
        if (t < NT - 1) asm volatile("s_waitcnt vmcnt(0)" ::: "memory");
        __builtin_amdgcn_s_barrier();
    }
#undef STG_A
#undef STG_B

    // epilogue: swapped layout -> acc[i][j] lane(quad,l16) reg r =
    // C[q = i*16+l16][d = j*16+quad*4+r]; bf16-packed partial stores.
    unsigned short* pslice = part + (size_t)z * NQ * DIM;
#pragma unroll
    for (int i = 0; i < 8; ++i) {
        int qrow = q0 + wm * 128 + i * 16 + l16;
#pragma unroll
        for (int j = 0; j < 4; ++j) {
            int dcol = d0 + wn * 64 + j * 16 + quad * 4;
            ushort4 v;
            v.x = f32_bf16(acc[i][j][0]); v.y = f32_bf16(acc[i][j][1]);
            v.z = f32_bf16(acc[i][j][2]); v.w = f32_bf16(acc[i][j][3]);
            *(ushort4*)&pslice[(size_t)qrow * DIM + dcol] = v;
        }
    }
}

// ---------------------------------------------------------------------------
// reduce: out[q][d] = (sum_z bf16 part[z][q][d]) / lsum[q]
// ---------------------------------------------------------------------------
__global__ void reduce_out(const unsigned short* __restrict__ part,
                           const float* __restrict__ lsum,
                           float* __restrict__ out) {
    size_t idx = ((size_t)blockIdx.x * 256 + threadIdx.x) * 4;
    int q = (int)(idx >> 10);
    float inv = 1.0f / lsum[q];
    const size_t S = (size_t)NQ * DIM;
    ushort4 a0 = *(const ushort4*)(part + idx);
    ushort4 a1 = *(const ushort4*)(part + S + idx);
    ushort4 a2 = *(const ushort4*)(part + 2 * S + idx);
    ushort4 a3 = *(const ushort4*)(part + 3 * S + idx);
    float4 o;
    o.x = (bf16_f32(a0.x) + bf16_f32(a1.x) + bf16_f32(a2.x) + bf16_f32(a3.x)) * inv;
    o.y = (bf16_f32(a0.y) + bf16_f32(a1.y) + bf16_f32(a2.y) + bf16_f32(a3.y)) * inv;
    o.z = (bf16_f32(a0.z) + bf16_f32(a1.z) + bf16_f32(a2.z) + bf16_f32(a3.z)) * inv;
    o.w = (bf16_f32(a0.w) + bf16_f32(a1.w) + bf16_f32(a2.w) + bf16_f32(a3.w)) * inv;
    *(float4*)(out + idx) = o;
}

// ---------------------------------------------------------------------------
// GEMM 2 tier-2 (exact R10): atomics into pre-zeroed out.
// ---------------------------------------------------------------------------
__global__ void ctx_gemm(const unsigned short* __restrict__ P,
                         const unsigned short* __restrict__ Kt,
                         const float* __restrict__ lsum,
                         float* __restrict__ out) {
    __shared__ __align__(16) unsigned short As[128 * 32];
    __shared__ __align__(16) unsigned short Bs[128 * 32];
    int id = blockIdx.x;
    int r8 = id & 7;
    int t  = id >> 3;
    int x  = t & 7;
    int g  = ((t >> 3) << 3) | r8;
    int y  = g & 31;
    int z  = g >> 5;
    int q0 = y * 128;
    int d0 = x * 128;
    int kbase = z * (NK / 4);

    int tid = threadIdx.x;
    int wave = tid >> 6, lane = tid & 63;
    int wm = wave >> 1, wn = wave & 1;
    int quad = lane >> 4, l16 = lane & 15;

    int srow   = wave * 32 + (lane >> 2);
    int schunk = (((lane & 3) ^ ((lane >> 3) & 3))) * 8;
    const unsigned short* gA0 = P + (size_t)(q0 + srow) * NK + kbase + schunk;
    const unsigned short* gA1 = gA0 + (size_t)16 * NK;
    const unsigned short* gB0 = Kt + (size_t)(d0 + srow) * NK + kbase + schunk;
    const unsigned short* gB1 = gB0 + (size_t)16 * NK;
    unsigned short* lA0 = As + wave * 32 * 32;
    unsigned short* lA1 = lA0 + 16 * 32;
    unsigned short* lB0 = Bs + wave * 32 * 32;
    unsigned short* lB1 = lB0 + 16 * 32;

    int rcol = (quad ^ ((l16 >> 1) & 3)) * 8;

    floatx4 acc[4][4];
#pragma unroll
    for (int i = 0; i < 4; ++i)
#pragma unroll
        for (int j = 0; j < 4; ++j) acc[i][j] = (floatx4)(0.0f);

    for (int kb = 0; kb < (NK / 4) / 32; ++kb) {
        int k0 = kb * 32;
        __syncthreads();
        gload_lds16(gA0 + k0, lA0);
        gload_lds16(gA1 + k0, lA1);
        gload_lds16(gB0 + k0, lB0);
        gload_lds16(gB1 + k0, lB1);
        __syncthreads();
        short8 a[4], b[4];
#pragma unroll
        for (int i = 0; i < 4; ++i)
            a[i] = *(const short8*)&As[(wm * 64 + i * 16 + l16) * 32 + rcol];
#pragma unroll
        for (int j = 0; j < 4; ++j)
            b[j] = *(const short8*)&Bs[(wn * 64 + j * 16 + l16) * 32 + rcol];
#pragma unroll
        for (int i = 0; i < 4; ++i)
#pragma unroll
            for (int j = 0; j < 4; ++j)
                acc[i][j] = __builtin_amdgcn_mfma_f32_16x16x32_bf16(a[i], b[j], acc[i][j], 0, 0, 0);
    }

#pragma unroll
    for (int i = 0; i < 4; ++i) {
        float invl[4];
#pragma unroll
        for (int r = 0; r < 4; ++r)
            invl[r] = 1.0f / lsum[q0 + wm * 64 + i * 16 + quad * 4 + r];
#pragma unroll
        for (int j = 0; j < 4; ++j) {
#pragma unroll
            for (int r = 0; r < 4; ++r) {
                int qrow = q0 + wm * 64 + i * 16 + quad * 4 + r;
                int dcol = d0 + wn * 64 + j * 16 + l16;
                atomicAdd(&out[(size_t)qrow * DIM + dcol], acc[i][j][r] * invl[r]);
            }
        }
    }
}

// ---------------------------------------------------------------------------
// Path D fallback (ws too small) — correct but slow.
// ---------------------------------------------------------------------------
__global__ void fused_fallback(const float* __restrict__ Q,
                               const float* __restrict__ K,
                               float* __restrict__ out) {
    int wave = threadIdx.x >> 6, lane = threadIdx.x & 63;
    int q0 = blockIdx.x * 16 + wave * 4;
    float qv[4][16], acc[4][16], iqn[4], ls[4];
#pragma unroll
    for (int r = 0; r < 4; ++r) {
        float s = 0.f;
#pragma unroll
        for (int c = 0; c < 4; ++c) {
            float4 f = *(const float4*)(Q + (size_t)(q0 + r) * DIM + c * 256 + lane * 4);
            qv[r][c * 4 + 0] = f.x; qv[r][c * 4 + 1] = f.y;
            qv[r][c * 4 + 2] = f.z; qv[r][c * 4 + 3] = f.w;
            s += f.x * f.x + f.y * f.y + f.z * f.z + f.w * f.w;
        }
#pragma unroll
        for (int off = 32; off > 0; off >>= 1) s += __shfl_xor(s, off);
        iqn[r] = 1.0f / sqrtf(s);
        ls[r] = 0.f;
#pragma unroll
        for (int t = 0; t < 16; ++t) acc[r][t] = 0.f;
    }
    for (int k = 0; k < NK; ++k) {
        const float* kr = K + (size_t)k * DIM;
        float kv[16], ss = 0.f;
#pragma unroll
        for (int c = 0; c < 4; ++c) {
            float4 f = *(const float4*)(kr + c * 256 + lane * 4);
            kv[c * 4 + 0] = f.x; kv[c * 4 + 1] = f.y;
            kv[c * 4 + 2] = f.z; kv[c * 4 + 3] = f.w;
            ss += f.x * f.x + f.y * f.y + f.z * f.z + f.w * f.w;
        }
        float d0 = 0.f, d1 = 0.f, d2 = 0.f, d3 = 0.f;
#pragma unroll
        for (int t = 0; t < 16; ++t) {
            d0 += qv[0][t] * kv[t]; d1 += qv[1][t] * kv[t];
            d2 += qv[2][t] * kv[t]; d3 += qv[3][t] * kv[t];
        }
#pragma unroll
        for (int off = 32; off > 0; off >>= 1) {
            ss += __shfl_xor(ss, off);
            d0 += __shfl_xor(d0, off); d1 += __shfl_xor(d1, off);
            d2 += __shfl_xor(d2, off); d3 += __shfl_xor(d3, off);
        }
        float ikn = 1.0f / sqrtf(ss);
        float p0 = __expf(d0 * iqn[0] * ikn), p1 = __expf(d1 * iqn[1] * ikn);
        float p2 = __expf(d2 * iqn[2] * ikn), p3 = __expf(d3 * iqn[3] * ikn);
        ls[0] += p0; ls[1] += p1; ls[2] += p2; ls[3] += p3;
#pragma unroll
        for (int t = 0; t < 16; ++t) {
            acc[0][t] += p0 * kv[t]; acc[1][t] += p1 * kv[t];
            acc[2][t] += p2 * kv[t]; acc[3][t] += p3 * kv[t];
        }
    }
#pragma unroll
    for (int r = 0; r < 4; ++r) {
        float inv = 1.0f / ls[r];
#pragma unroll
        for (int c = 0; c < 4; ++c) {
            float4 o;
            o.x = acc[r][c * 4 + 0] * inv; o.y = acc[r][c * 4 + 1] * inv;
            o.z = acc[r][c * 4 + 2] * inv; o.w = acc[r][c * 4 + 3] * inv;
            *(float4*)(out + (size_t)(q0 + r) * DIM + c * 256 + lane * 4) = o;
        }
    }
}

// ---------------------------------------------------------------------------
// launch — tiers:
//  T1 (ws>=152M+64K): Qb[0,8M) Kb[8,24M) P[24,88M) part_bf16[88,120M)
//                     Kt[120,136M) scalars @152M; prep_all + transpose_bf16
//                     + score + ctx_gemm_st + reduce_out.
//  T2 (ws>=88M+64K):  legacy aliased layout (Kt@0 after score), atomics.
//  else: fallback.
// ---------------------------------------------------------------------------
extern "C" void kernel_launch(void* const* d_in, const int* in_sizes, int n_in,
                              void* d_out, int out_size, void* d_ws, size_t ws_size,
                              hipStream_t stream) {
    const float* Q = (const float*)d_in[0];
    const float* K = (const float*)d_in[1];
    float* out = (float*)d_out;
    char* ws = (char*)d_ws;

    const size_t REQ_T1 = ((size_t)152u << 20) + 65536;
    const size_t REQ_T2 = ((size_t)88u << 20) + 65536;

    if (ws_size >= REQ_T1) {
        unsigned short* Qb = (unsigned short*)(ws);
        unsigned short* Kb = (unsigned short*)(ws + (size_t)(8u << 20));
        unsigned short* P  = (unsigned short*)(ws + (size_t)(24u << 20));
        unsigned short* part = (unsigned short*)(ws + (size_t)(88u << 20));
        unsigned short* Kt = (unsigned short*)(ws + (size_t)(120u << 20));
        float* inv_qn = (float*)(ws + (size_t)(152u << 20));
        float* inv_kn = (float*)(ws + (size_t)(152u << 20) + 16384);
        float* lsum   = (float*)(ws + (size_t)(152u << 20) + 49152);

        prep_all<<<NQ / 4 + NK / 4, 256, 0, stream>>>(Q, K, Qb, Kb, inv_qn, inv_kn, lsum, nullptr);
        transpose_bf16<<<dim3(NK / 64, DIM / 64), 256, 0, stream>>>(Kb, Kt);
        score_gemm<<<512, 512, 0, stream>>>(Qb, Kb, inv_qn, inv_kn, P, lsum);
        ctx_gemm_st<<<256, 512, 0, stream>>>(P, Kt, part);
        reduce_out<<<NQ * DIM / 1024, 256, 0, stream>>>(part, lsum, out);
    } else if (ws_size >= REQ_T2) {
        unsigned short* Kt = (unsigned short*)(ws);
        unsigned short* Qb = (unsigned short*)(ws);
        unsigned short* Kb = (unsigned short*)(ws + (size_t)(8u << 20));
        unsigned short* P  = (unsigned short*)(ws + (size_t)(24u << 20));
        float* inv_qn = (float*)(ws + (size_t)(88u << 20));
        float* inv_kn = (float*)(ws + (size_t)(88u << 20) + 16384);
        float* lsum   = (float*)(ws + (size_t)(88u << 20) + 49152);

        prep_all<<<NQ / 4 + NK / 4, 256, 0, stream>>>(Q, K, Qb, Kb, inv_qn, inv_kn, lsum, out);
        score_gemm<<<512, 512, 0, stream>>>(Qb, Kb, inv_qn, inv_kn, P, lsum);
        transpose_cvt<<<dim3(NK / 64, DIM / 64), 256, 0, stream>>>(K, Kt);
        ctx_gemm<<<1024, 256, 0, stream>>>(P, Kt, lsum, out);
    } else {
        fused_fallback<<<NQ / 16, 256, 0, stream>>>(Q, K, out);
    }
}